// Round 4
// baseline (275.565 us; speedup 1.0000x reference)
//
#include <hip/hip_runtime.h>
#include <cstdint>
#include <cstddef>

typedef unsigned short u16;
typedef __attribute__((ext_vector_type(8))) short bf16x8;
typedef __attribute__((ext_vector_type(4))) float f32x4;

__device__ inline float bl(uint32_t u){ union{float f;uint32_t i;}c; c.i = u<<16; return c.f; }
__device__ inline float bh(uint32_t u){ union{float f;uint32_t i;}c; c.i = u & 0xFFFF0000u; return c.f; }
__device__ inline u16 f2bu(float f){
  union{float f;uint32_t u;} c; c.f=f;
  uint32_t u=c.u;
  return (u16)((u + 0x7FFFu + ((u>>16)&1u))>>16);  // RNE
}

#define GLOAD_LDS16(g, l) __builtin_amdgcn_global_load_lds( \
    (__attribute__((address_space(1))) void*)(g), \
    (__attribute__((address_space(3))) void*)(l), 16, 0, 0)
#define BAR() do{ asm volatile("" ::: "memory"); __builtin_amdgcn_s_barrier(); asm volatile("" ::: "memory"); }while(0)

// ---------------- convert x: f32 -> bf16 ----------------
__global__ __launch_bounds__(256) void k_conv_x(const float* __restrict__ X,
                                                u16* __restrict__ Xb, int n4){
  int i = blockIdx.x*256 + threadIdx.x;
  int stride = gridDim.x*256;
  for (; i < n4; i += stride){
    float4 v = ((const float4*)X)[i];
    ushort4 o;
    o.x=f2bu(v.x); o.y=f2bu(v.y); o.z=f2bu(v.z); o.w=f2bu(v.w);
    ((ushort4*)Xb)[i] = o;
  }
}

// ---------------- transpose+convert W: [1024][3072] f32 -> [3072][1024] bf16 ----------------
__global__ __launch_bounds__(256) void k_conv_wt(const float* __restrict__ W,
                                                 u16* __restrict__ Wt){
  __shared__ float t[32][33];
  int n0 = blockIdx.x*32, k0 = blockIdx.y*32;
  int tx = threadIdx.x & 31, ty = threadIdx.x >> 5;
  #pragma unroll
  for (int i=0;i<32;i+=8)
    t[ty+i][tx] = W[(size_t)(k0+ty+i)*3072 + n0+tx];
  __syncthreads();
  #pragma unroll
  for (int i=0;i<32;i+=8)
    Wt[(size_t)(n0+ty+i)*1024 + k0+tx] = f2bu(t[tx][ty+i]);
}

// ---------------- GEMM: Qkv[M=16384][N=3072] = Xb[M][K]*Wt[N][K]^T + bias, bf16 out ------------
// 256x256 tile, BK=32, 8 waves (2Mx4N), 3-deep LDS pipeline (96KB), counted vmcnt(4),
// setprio around MFMA clusters, conflict-free blocked LDS layout [kchunk(4)][row(256)][8elem].
__global__ __launch_bounds__(512, 2) void k_gemm2(const u16* __restrict__ Xb,
                                                  const u16* __restrict__ Wt,
                                                  const float* __restrict__ bias,
                                                  u16* __restrict__ Q){
  __shared__ __align__(16) u16 As[3][8192];
  __shared__ __align__(16) u16 Bs[3][8192];
  const int K = 1024, N = 3072, NT = 32;
  int b = blockIdx.x;
  // XCD swizzle: nwg=768, 768%8==0 -> bijective
  int swz = (b & 7)*96 + (b >> 3);
  int bm = swz / 12, bn = swz % 12;
  int m0 = bm*256, n0 = bn*256;
  int tid = threadIdx.x, w = tid>>6, lane = tid&63;
  int lr = lane&15, lk = lane>>4;
  int wm = w>>2, wn = w&3;

  // per-lane stage source offsets: LDS byte p -> kchunk=p>>12, row=(p>>4)&255, 16B contiguous
  int p0 = (w*2+0)*1024 + lane*16;
  int p1 = (w*2+1)*1024 + lane*16;
  const u16* xa0 = Xb + (size_t)(m0 + ((p0>>4)&255))*K + ((p0>>12)*8);
  const u16* xa1 = Xb + (size_t)(m0 + ((p1>>4)&255))*K + ((p1>>12)*8);
  const u16* wb0 = Wt + (size_t)(n0 + ((p0>>4)&255))*K + ((p0>>12)*8);
  const u16* wb1 = Wt + (size_t)(n0 + ((p1>>4)&255))*K + ((p1>>12)*8);
  int ldst0 = (w*2+0)*512;   // u16 elements
  int ldst1 = (w*2+1)*512;

  f32x4 acc[8][4];
  #pragma unroll
  for (int i=0;i<8;i++)
    #pragma unroll
    for (int j=0;j<4;j++)
      acc[i][j] = (f32x4){0.f,0.f,0.f,0.f};

  // read bases (elements): frag (row-tile ti): lk*2048 + (base + ti*16 + lr)*8
  int abase = lk*2048 + (wm*128 + lr)*8;
  int bbase = lk*2048 + (wn*64  + lr)*8;

#define STAGE(t) do{ int bi=(t)%3; int kt=(t)*32; \
    GLOAD_LDS16(xa0 + kt, &As[bi][ldst0]); \
    GLOAD_LDS16(xa1 + kt, &As[bi][ldst1]); \
    GLOAD_LDS16(wb0 + kt, &Bs[bi][ldst0]); \
    GLOAD_LDS16(wb1 + kt, &Bs[bi][ldst1]); }while(0)

  STAGE(0); STAGE(1);
  asm volatile("s_waitcnt vmcnt(4)" ::: "memory");
  BAR();

  for (int t=0; t<NT; ++t){
    const u16* Ab = As[t%3];
    const u16* Bb = Bs[t%3];
    bf16x8 bfr[4], afr[4];
    #pragma unroll
    for (int nf=0; nf<4; ++nf) bfr[nf] = *(const bf16x8*)&Bb[bbase + nf*128];
    #pragma unroll
    for (int mi=0; mi<4; ++mi) afr[mi] = *(const bf16x8*)&Ab[abase + mi*128];
    if (t+2 < NT) STAGE(t+2);
    __builtin_amdgcn_s_setprio(1);
    #pragma unroll
    for (int mi=0; mi<4; ++mi)
      #pragma unroll
      for (int nf=0; nf<4; ++nf)
        acc[mi][nf] = __builtin_amdgcn_mfma_f32_16x16x32_bf16(afr[mi], bfr[nf], acc[mi][nf], 0,0,0);
    __builtin_amdgcn_s_setprio(0);
    BAR();
    // phase B: rows 4-7 (reuse bfr)
    #pragma unroll
    for (int mi=0; mi<4; ++mi) afr[mi] = *(const bf16x8*)&Ab[abase + (mi+4)*128];
    __builtin_amdgcn_s_setprio(1);
    #pragma unroll
    for (int mi=0; mi<4; ++mi)
      #pragma unroll
      for (int nf=0; nf<4; ++nf)
        acc[mi+4][nf] = __builtin_amdgcn_mfma_f32_16x16x32_bf16(afr[mi], bfr[nf], acc[mi+4][nf], 0,0,0);
    __builtin_amdgcn_s_setprio(0);
    if (t < NT-1){
      if (t+2 < NT) { asm volatile("s_waitcnt vmcnt(4)" ::: "memory"); }
      else          { asm volatile("s_waitcnt vmcnt(0)" ::: "memory"); }
      BAR();
    }
  }
#undef STAGE

  // epilogue: C/D layout col=lane&15, row=(lane>>4)*4+reg
  #pragma unroll
  for (int nf=0; nf<4; ++nf){
    int col = n0 + wn*64 + nf*16 + lr;
    float bv = bias[col];
    #pragma unroll
    for (int mi=0; mi<8; ++mi){
      int rowb = m0 + wm*128 + mi*16 + lk*4;
      #pragma unroll
      for (int r=0;r<4;r++){
        Q[(size_t)(rowb+r)*N + col] = f2bu(acc[mi][nf][r] + bv);
      }
    }
  }
}

// ---------------- per-token head-attention (bf16 qkv input) ----------------
__device__ inline void load16fb(const u16* p, float* f){
  uint4 a = ((const uint4*)p)[0], b4 = ((const uint4*)p)[1];
  f[0]=bl(a.x);  f[1]=bh(a.x);  f[2]=bl(a.y);  f[3]=bh(a.y);
  f[4]=bl(a.z);  f[5]=bh(a.z);  f[6]=bl(a.w);  f[7]=bh(a.w);
  f[8]=bl(b4.x); f[9]=bh(b4.x); f[10]=bl(b4.y);f[11]=bh(b4.y);
  f[12]=bl(b4.z);f[13]=bh(b4.z);f[14]=bl(b4.w);f[15]=bh(b4.w);
}

// 1 wave per token; lane = h*4 + dq; dq owns d in [dq*16, dq*16+16).
__global__ __launch_bounds__(256) void k_attn(const u16* __restrict__ Qkv,
                                              float* __restrict__ out){
  __shared__ __align__(16) u16 sm[4][3072];
  int w = threadIdx.x>>6, lane = threadIdx.x&63;
  int token = blockIdx.x*4 + w;
  const uint4* src = (const uint4*)(Qkv + (size_t)token*3072);
  uint4* dst = (uint4*)&sm[w][0];
  for (int i = lane; i < 384; i += 64) dst[i] = src[i];
  __syncthreads();

  int h = lane>>2, dq = lane&3;
  const u16* base = &sm[w][0];
  float qf[16];
  load16fb(base + h*192 + dq*16, qf);

  const float scale = 0.07216878364870323f;  // 1/sqrt(192)
  float s[16];
  #pragma unroll
  for (int g=0; g<16; ++g){
    float kf[16];
    load16fb(base + g*192 + 64 + dq*16, kf);
    float a = 0.f;
    #pragma unroll
    for (int j=0;j<16;j++) a += qf[j]*kf[j];
    a += __shfl_xor(a, 1);
    a += __shfl_xor(a, 2);
    s[g] = a * scale;
  }
  float mx = s[0];
  #pragma unroll
  for (int g=1; g<16; ++g) mx = fmaxf(mx, s[g]);
  float sum = 0.f;
  #pragma unroll
  for (int g=0; g<16; ++g){ s[g] = __expf(s[g]-mx); sum += s[g]; }
  float inv = 1.f/sum;

  float o[16];
  #pragma unroll
  for (int j=0;j<16;j++) o[j] = 0.f;
  #pragma unroll
  for (int g=0; g<16; ++g){
    float wg = s[g]*inv;
    float vf[16];
    load16fb(base + g*192 + 128 + dq*16, vf);
    #pragma unroll
    for (int j=0;j<16;j++) o[j] += wg*vf[j];
  }
  float* op = out + (size_t)token*1024 + h*64 + dq*16;
  #pragma unroll
  for (int i=0;i<4;i++)
    ((float4*)op)[i] = make_float4(o[i*4], o[i*4+1], o[i*4+2], o[i*4+3]);
}

// ---------------- fallback (ws too small): fully fused, f32 VALU, slow but correct ----------------
__global__ __launch_bounds__(256) void k_fallback(const float* __restrict__ X,
                                                  const float* __restrict__ W,
                                                  const float* __restrict__ bias,
                                                  float* __restrict__ out){
  int token = blockIdx.x;
  __shared__ float xs[1024];
  __shared__ float qkvs[3072];
  __shared__ float ss[16][16];
  __shared__ float ww[16][16];
  for (int i=threadIdx.x; i<1024; i+=256) xs[i] = X[(size_t)token*1024 + i];
  __syncthreads();
  for (int n=threadIdx.x; n<3072; n+=256){
    float acc = bias[n];
    for (int k=0;k<1024;k++) acc += xs[k]*W[(size_t)k*3072 + n];
    qkvs[n] = acc;
  }
  __syncthreads();
  {
    int t = threadIdx.x, h = t>>4, g = t&15;
    float a = 0.f;
    for (int d=0; d<64; d++) a += qkvs[h*192 + d]*qkvs[g*192 + 64 + d];
    ss[h][g] = a * 0.07216878364870323f;
  }
  __syncthreads();
  if (threadIdx.x < 16){
    int hh = threadIdx.x;
    float m = -1e30f;
    for (int g=0;g<16;g++) m = fmaxf(m, ss[hh][g]);
    float sum = 0.f;
    for (int g=0;g<16;g++){ float e = __expf(ss[hh][g]-m); ww[hh][g]=e; sum+=e; }
    float inv = 1.f/sum;
    for (int g=0;g<16;g++) ww[hh][g] *= inv;
  }
  __syncthreads();
  for (int i=threadIdx.x; i<1024; i+=256){
    int h = i>>6, d = i&63;
    float a = 0.f;
    for (int g=0;g<16;g++) a += ww[h][g]*qkvs[g*192 + 128 + d];
    out[(size_t)token*1024 + i] = a;
  }
}

extern "C" void kernel_launch(void* const* d_in, const int* in_sizes, int n_in,
                              void* d_out, int out_size, void* d_ws, size_t ws_size,
                              hipStream_t stream){
  const float* x    = (const float*)d_in[0];   // [4,4096,1024] f32
  const float* wk   = (const float*)d_in[1];   // [1024,16,192] f32
  const float* bias = (const float*)d_in[2];   // [16,192] f32
  float* out = (float*)d_out;                  // [4,4096,16,64] f32

  const size_t offW = 33554432;                       // Xb: 16M bf16
  const size_t offQ = offW + 6291456;                 // Wt: 3M bf16
  const size_t need = offQ + (size_t)16384*3072*2;    // Q bf16

  if (ws_size >= need){
    u16* Xb = (u16*)d_ws;
    u16* Wt = (u16*)((char*)d_ws + offW);
    u16* Q  = (u16*)((char*)d_ws + offQ);
    k_conv_x <<<2048, 256, 0, stream>>>(x, Xb, 16777216/4);
    k_conv_wt<<<dim3(96,32), 256, 0, stream>>>(wk, Wt);
    k_gemm2  <<<768, 512, 0, stream>>>(Xb, Wt, bias, Q);
    k_attn   <<<4096, 256, 0, stream>>>(Q, out);
  } else {
    k_fallback<<<16384, 256, 0, stream>>>(x, wk, bias, out);
  }
}

// Round 5
// 275.387 us; speedup vs baseline: 1.0006x; 1.0006x over previous
//
#include <hip/hip_runtime.h>
#include <cstdint>
#include <cstddef>

typedef unsigned short u16;
typedef __attribute__((ext_vector_type(8))) short bf16x8;
typedef __attribute__((ext_vector_type(4))) float f32x4;

__device__ inline float bl(uint32_t u){ union{float f;uint32_t i;}c; c.i = u<<16; return c.f; }
__device__ inline float bh(uint32_t u){ union{float f;uint32_t i;}c; c.i = u & 0xFFFF0000u; return c.f; }
__device__ inline u16 f2bu(float f){
  union{float f;uint32_t u;} c; c.f=f;
  uint32_t u=c.u;
  return (u16)((u + 0x7FFFu + ((u>>16)&1u))>>16);  // RNE
}

#define GLOAD_LDS16(g, l) __builtin_amdgcn_global_load_lds( \
    (__attribute__((address_space(1))) void*)(g), \
    (__attribute__((address_space(3))) void*)(l), 16, 0, 0)

// ---------------- convert x: f32 -> bf16 ----------------
__global__ __launch_bounds__(256) void k_conv_x(const float* __restrict__ X,
                                                u16* __restrict__ Xb, int n4){
  int i = blockIdx.x*256 + threadIdx.x;
  int stride = gridDim.x*256;
  for (; i < n4; i += stride){
    float4 v = ((const float4*)X)[i];
    ushort4 o;
    o.x=f2bu(v.x); o.y=f2bu(v.y); o.z=f2bu(v.z); o.w=f2bu(v.w);
    ((ushort4*)Xb)[i] = o;
  }
}

// ---------------- transpose+convert W: [1024][3072] f32 -> [3072][1024] bf16 ----------------
__global__ __launch_bounds__(256) void k_conv_wt(const float* __restrict__ W,
                                                 u16* __restrict__ Wt){
  __shared__ float t[32][33];
  int n0 = blockIdx.x*32, k0 = blockIdx.y*32;
  int tx = threadIdx.x & 31, ty = threadIdx.x >> 5;
  #pragma unroll
  for (int i=0;i<32;i+=8)
    t[ty+i][tx] = W[(size_t)(k0+ty+i)*3072 + n0+tx];
  __syncthreads();
  #pragma unroll
  for (int i=0;i<32;i+=8)
    Wt[(size_t)(n0+ty+i)*1024 + k0+tx] = f2bu(t[tx][ty+i]);
}

// ---------------- GEMM: Qkv[M=16384][N=3072] = Xb[M][K=1024]*Wt[N][K]^T + bias, bf16 out ------
// m97 structure (round-3 verified, 142us): 128x128 tile, BK=32, 4 waves, 4x4 frags,
// global_load_lds width=16. Round-4-verified blocked LDS layout [kchunk(4)][row(128)][8elem]
// -> zero bank conflicts. bf16 output (round-4-verified numerics) halves WRITE_SIZE.
__global__ __launch_bounds__(256) void k_gemm(const u16* __restrict__ Xb,
                                              const u16* __restrict__ Wt,
                                              const float* __restrict__ bias,
                                              u16* __restrict__ Q){
  __shared__ __align__(16) u16 As[4096];   // [kchunk w][row 128][8 elems]
  __shared__ __align__(16) u16 Bs[4096];
  const int K = 1024, N = 3072;
  int b = blockIdx.x;
  // XCD-aware swizzle (nwg=3072, 3072%8==0 -> bijective)
  int swz = (b & 7)*384 + (b >> 3);
  int bm = swz / 24, bn = swz % 24;
  int m0 = bm*128, n0 = bn*128;
  int tid = threadIdx.x, w = tid>>6, lane = tid&63, lr = lane&15, lk = lane>>4;
  int wr = w>>1, wc = w&1;

  f32x4 acc[4][4];
  #pragma unroll
  for (int i=0;i<4;i++)
    #pragma unroll
    for (int j=0;j<4;j++)
      acc[i][j] = (f32x4){0.f,0.f,0.f,0.f};

  // staging (blocked layout): wave w owns kchunk w (k-elems [w*8, w*8+8) of the BK=32 step).
  // load 0: rows 0..63 (lane -> row lane), load 1: rows 64..127.
  const u16* gA0 = Xb + (size_t)(m0 + lane)*K      + w*8;
  const u16* gA1 = Xb + (size_t)(m0 + 64 + lane)*K + w*8;
  const u16* gB0 = Wt + (size_t)(n0 + lane)*K      + w*8;
  const u16* gB1 = Wt + (size_t)(n0 + 64 + lane)*K + w*8;
  u16* lA0 = &As[w*1024];        u16* lA1 = &As[w*1024 + 512];
  u16* lB0 = &Bs[w*1024];        u16* lB1 = &Bs[w*1024 + 512];

  for (int kt = 0; kt < K; kt += 32){
    GLOAD_LDS16(gA0 + kt, lA0);
    GLOAD_LDS16(gA1 + kt, lA1);
    GLOAD_LDS16(gB0 + kt, lB0);
    GLOAD_LDS16(gB1 + kt, lB1);
    __syncthreads();   // drains vmcnt before reads

    // frag reads: lane(lr,lk) reads row (tilebase+lr), kchunk lk -> 16 lanes x 16B contiguous
    // per quarter-wave = conflict-free (round-4 measured: 0 conflicts).
    bf16x8 af[4], bfr[4];
    #pragma unroll
    for (int mi=0;mi<4;mi++)
      af[mi] = *(const bf16x8*)&As[lk*1024 + (wr*64 + mi*16 + lr)*8];
    #pragma unroll
    for (int ni=0;ni<4;ni++)
      bfr[ni] = *(const bf16x8*)&Bs[lk*1024 + (wc*64 + ni*16 + lr)*8];
    #pragma unroll
    for (int mi=0;mi<4;mi++)
      #pragma unroll
      for (int ni=0;ni<4;ni++)
        acc[mi][ni] = __builtin_amdgcn_mfma_f32_16x16x32_bf16(af[mi], bfr[ni], acc[mi][ni], 0, 0, 0);
    __syncthreads();   // protect LDS before next stage
  }

  // epilogue: C/D layout col=lane&15, row=(lane>>4)*4+reg  [m89-verified]
  #pragma unroll
  for (int ni=0;ni<4;ni++){
    int col = n0 + wc*64 + ni*16 + lr;
    float bv = bias[col];
    #pragma unroll
    for (int mi=0;mi<4;mi++){
      int rowb = m0 + wr*64 + mi*16 + lk*4;
      #pragma unroll
      for (int r=0;r<4;r++){
        Q[(size_t)(rowb + r)*N + col] = f2bu(acc[mi][ni][r] + bv);
      }
    }
  }
}

// ---------------- per-token head-attention (bf16 qkv input; round-4 verified) ----------------
__device__ inline void load16fb(const u16* p, float* f){
  uint4 a = ((const uint4*)p)[0], b4 = ((const uint4*)p)[1];
  f[0]=bl(a.x);  f[1]=bh(a.x);  f[2]=bl(a.y);  f[3]=bh(a.y);
  f[4]=bl(a.z);  f[5]=bh(a.z);  f[6]=bl(a.w);  f[7]=bh(a.w);
  f[8]=bl(b4.x); f[9]=bh(b4.x); f[10]=bl(b4.y);f[11]=bh(b4.y);
  f[12]=bl(b4.z);f[13]=bh(b4.z);f[14]=bl(b4.w);f[15]=bh(b4.w);
}

// 1 wave per token; lane = h*4 + dq; dq owns d in [dq*16, dq*16+16).
__global__ __launch_bounds__(256) void k_attn(const u16* __restrict__ Qkv,
                                              float* __restrict__ out){
  __shared__ __align__(16) u16 sm[4][3072];
  int w = threadIdx.x>>6, lane = threadIdx.x&63;
  int token = blockIdx.x*4 + w;
  const uint4* src = (const uint4*)(Qkv + (size_t)token*3072);
  uint4* dst = (uint4*)&sm[w][0];
  for (int i = lane; i < 384; i += 64) dst[i] = src[i];
  __syncthreads();

  int h = lane>>2, dq = lane&3;
  const u16* base = &sm[w][0];
  float qf[16];
  load16fb(base + h*192 + dq*16, qf);

  const float scale = 0.07216878364870323f;  // 1/sqrt(192)
  float s[16];
  #pragma unroll
  for (int g=0; g<16; ++g){
    float kf[16];
    load16fb(base + g*192 + 64 + dq*16, kf);
    float a = 0.f;
    #pragma unroll
    for (int j=0;j<16;j++) a += qf[j]*kf[j];
    a += __shfl_xor(a, 1);
    a += __shfl_xor(a, 2);
    s[g] = a * scale;
  }
  float mx = s[0];
  #pragma unroll
  for (int g=1; g<16; ++g) mx = fmaxf(mx, s[g]);
  float sum = 0.f;
  #pragma unroll
  for (int g=0; g<16; ++g){ s[g] = __expf(s[g]-mx); sum += s[g]; }
  float inv = 1.f/sum;

  float o[16];
  #pragma unroll
  for (int j=0;j<16;j++) o[j] = 0.f;
  #pragma unroll
  for (int g=0; g<16; ++g){
    float wg = s[g]*inv;
    float vf[16];
    load16fb(base + g*192 + 128 + dq*16, vf);
    #pragma unroll
    for (int j=0;j<16;j++) o[j] += wg*vf[j];
  }
  float* op = out + (size_t)token*1024 + h*64 + dq*16;
  #pragma unroll
  for (int i=0;i<4;i++)
    ((float4*)op)[i] = make_float4(o[i*4], o[i*4+1], o[i*4+2], o[i*4+3]);
}

// ---------------- fallback (ws too small): fully fused, f32 VALU, slow but correct ----------------
__global__ __launch_bounds__(256) void k_fallback(const float* __restrict__ X,
                                                  const float* __restrict__ W,
                                                  const float* __restrict__ bias,
                                                  float* __restrict__ out){
  int token = blockIdx.x;
  __shared__ float xs[1024];
  __shared__ float qkvs[3072];
  __shared__ float ss[16][16];
  __shared__ float ww[16][16];
  for (int i=threadIdx.x; i<1024; i+=256) xs[i] = X[(size_t)token*1024 + i];
  __syncthreads();
  for (int n=threadIdx.x; n<3072; n+=256){
    float acc = bias[n];
    for (int k=0;k<1024;k++) acc += xs[k]*W[(size_t)k*3072 + n];
    qkvs[n] = acc;
  }
  __syncthreads();
  {
    int t = threadIdx.x, h = t>>4, g = t&15;
    float a = 0.f;
    for (int d=0; d<64; d++) a += qkvs[h*192 + d]*qkvs[g*192 + 64 + d];
    ss[h][g] = a * 0.07216878364870323f;
  }
  __syncthreads();
  if (threadIdx.x < 16){
    int hh = threadIdx.x;
    float m = -1e30f;
    for (int g=0;g<16;g++) m = fmaxf(m, ss[hh][g]);
    float sum = 0.f;
    for (int g=0;g<16;g++){ float e = __expf(ss[hh][g]-m); ww[hh][g]=e; sum+=e; }
    float inv = 1.f/sum;
    for (int g=0;g<16;g++) ww[hh][g] *= inv;
  }
  __syncthreads();
  for (int i=threadIdx.x; i<1024; i+=256){
    int h = i>>6, d = i&63;
    float a = 0.f;
    for (int g=0;g<16;g++) a += ww[h][g]*qkvs[g*192 + 128 + d];
    out[(size_t)token*1024 + i] = a;
  }
}

extern "C" void kernel_launch(void* const* d_in, const int* in_sizes, int n_in,
                              void* d_out, int out_size, void* d_ws, size_t ws_size,
                              hipStream_t stream){
  const float* x    = (const float*)d_in[0];   // [4,4096,1024] f32
  const float* wk   = (const float*)d_in[1];   // [1024,16,192] f32
  const float* bias = (const float*)d_in[2];   // [16,192] f32
  float* out = (float*)d_out;                  // [4,4096,16,64] f32

  const size_t offW = 33554432;                       // Xb: 16M bf16
  const size_t offQ = offW + 6291456;                 // Wt: 3M bf16
  const size_t need = offQ + (size_t)16384*3072*2;    // Q bf16

  if (ws_size >= need){
    u16* Xb = (u16*)d_ws;
    u16* Wt = (u16*)((char*)d_ws + offW);
    u16* Q  = (u16*)((char*)d_ws + offQ);
    k_conv_x <<<2048, 256, 0, stream>>>(x, Xb, 16777216/4);
    k_conv_wt<<<dim3(96,32), 256, 0, stream>>>(wk, Wt);
    k_gemm   <<<3072, 256, 0, stream>>>(Xb, Wt, bias, Q);
    k_attn   <<<4096, 256, 0, stream>>>(Q, out);
  } else {
    k_fallback<<<16384, 256, 0, stream>>>(x, wk, bias, out);
  }
}

// Round 7
// 206.516 us; speedup vs baseline: 1.3344x; 1.3335x over previous
//
#include <hip/hip_runtime.h>
#include <cstdint>
#include <cstddef>

typedef unsigned short u16;
typedef __attribute__((ext_vector_type(8))) short bf16x8;
typedef __attribute__((ext_vector_type(4))) float f32x4;

__device__ inline float bl(uint32_t u){ union{float f;uint32_t i;}c; c.i = u<<16; return c.f; }
__device__ inline float bh(uint32_t u){ union{float f;uint32_t i;}c; c.i = u & 0xFFFF0000u; return c.f; }
__device__ inline u16 f2bu(float f){
  union{float f;uint32_t u;} c; c.f=f;
  uint32_t u=c.u;
  return (u16)((u + 0x7FFFu + ((u>>16)&1u))>>16);  // RNE
}

#define GLOAD_LDS16(g, l) __builtin_amdgcn_global_load_lds( \
    (__attribute__((address_space(1))) void*)(g), \
    (__attribute__((address_space(3))) void*)(l), 16, 0, 0)

// ---------------- convert x: f32 -> bf16 ----------------
__global__ __launch_bounds__(256) void k_conv_x(const float* __restrict__ X,
                                                u16* __restrict__ Xb, int n4){
  int i = blockIdx.x*256 + threadIdx.x;
  int stride = gridDim.x*256;
  for (; i < n4; i += stride){
    float4 v = ((const float4*)X)[i];
    ushort4 o;
    o.x=f2bu(v.x); o.y=f2bu(v.y); o.z=f2bu(v.z); o.w=f2bu(v.w);
    ((ushort4*)Xb)[i] = o;
  }
}

// ---------------- transpose+convert W: [1024][3072] f32 -> [3072][1024] bf16 ----------------
__global__ __launch_bounds__(256) void k_conv_wt(const float* __restrict__ W,
                                                 u16* __restrict__ Wt){
  __shared__ float t[32][33];
  int n0 = blockIdx.x*32, k0 = blockIdx.y*32;
  int tx = threadIdx.x & 31, ty = threadIdx.x >> 5;
  #pragma unroll
  for (int i=0;i<32;i+=8)
    t[ty+i][tx] = W[(size_t)(k0+ty+i)*3072 + n0+tx];
  __syncthreads();
  #pragma unroll
  for (int i=0;i<32;i+=8)
    Wt[(size_t)(n0+ty+i)*1024 + k0+tx] = f2bu(t[tx][ty+i]);
}

// ---------------- GEMM: Qkv[M=16384][N=3072] = Xb[M][K=1024]*Wt[N][K]^T + bias, bf16 out ------
// EXACT round-3 structure (verified 142us, MfmaUtil 31%): 128x128 tile, BK=32, 4 waves,
// 4x4 frags of 16x16x32 bf16 MFMA, coalesced global_load_lds (64B/row segments, 16 rows/load),
// linear LDS [row][32k]. Only delta vs round 3: bf16 output (round-4/5-verified numerics,
// halves WRITE_SIZE). Round-5 lesson: do NOT trade global coalescing for LDS conflicts here.
__global__ __launch_bounds__(256) void k_gemm(const u16* __restrict__ Xb,
                                              const u16* __restrict__ Wt,
                                              const float* __restrict__ bias,
                                              u16* __restrict__ Q){
  __shared__ __align__(16) u16 As[128*32];
  __shared__ __align__(16) u16 Bs[128*32];
  const int K = 1024, N = 3072;
  int b = blockIdx.x;
  // XCD-aware swizzle (nwg=3072, 3072%8==0 -> bijective)
  int swz = (b & 7)*384 + (b >> 3);
  int bm = swz / 24, bn = swz % 24;
  int m0 = bm*128, n0 = bn*128;
  int tid = threadIdx.x, w = tid>>6, lane = tid&63, lr = lane&15, lk = lane>>4;
  int wr = w>>1, wc = w&1;

  f32x4 acc[4][4];
  #pragma unroll
  for (int i=0;i<4;i++)
    #pragma unroll
    for (int j=0;j<4;j++)
      acc[i][j] = (f32x4){0.f,0.f,0.f,0.f};

  // staging: 8 chunks of 1024B per matrix; wave w owns chunks 2w, 2w+1.
  int e0 = (2*w)*512 + lane*8;   // bf16 element index within tile (linear [row][32k])
  int e1 = e0 + 512;
  const u16* gA0 = Xb + (size_t)(m0 + (e0>>5))*K + (e0&31);
  const u16* gA1 = Xb + (size_t)(m0 + (e1>>5))*K + (e1&31);
  const u16* gB0 = Wt + (size_t)(n0 + (e0>>5))*K + (e0&31);
  const u16* gB1 = Wt + (size_t)(n0 + (e1>>5))*K + (e1&31);
  u16* lA0 = &As[(2*w)*512]; u16* lA1 = &As[(2*w)*512 + 512];
  u16* lB0 = &Bs[(2*w)*512]; u16* lB1 = &Bs[(2*w)*512 + 512];

  for (int kt = 0; kt < K; kt += 32){
    GLOAD_LDS16(gA0 + kt, lA0);
    GLOAD_LDS16(gA1 + kt, lA1);
    GLOAD_LDS16(gB0 + kt, lB0);
    GLOAD_LDS16(gB1 + kt, lB1);
    __syncthreads();   // drains vmcnt before reads

    bf16x8 af[4], bfr[4];
    #pragma unroll
    for (int mi=0;mi<4;mi++)
      af[mi] = *(const bf16x8*)&As[(wr*64 + mi*16 + lr)*32 + lk*8];
    #pragma unroll
    for (int ni=0;ni<4;ni++)
      bfr[ni] = *(const bf16x8*)&Bs[(wc*64 + ni*16 + lr)*32 + lk*8];
    #pragma unroll
    for (int mi=0;mi<4;mi++)
      #pragma unroll
      for (int ni=0;ni<4;ni++)
        acc[mi][ni] = __builtin_amdgcn_mfma_f32_16x16x32_bf16(af[mi], bfr[ni], acc[mi][ni], 0, 0, 0);
    __syncthreads();   // protect LDS before next stage
  }

  // epilogue: C/D layout col=lane&15, row=(lane>>4)*4+reg  [m89-verified]
  #pragma unroll
  for (int ni=0;ni<4;ni++){
    int col = n0 + wc*64 + ni*16 + lr;
    float bv = bias[col];
    #pragma unroll
    for (int mi=0;mi<4;mi++){
      int rowb = m0 + wr*64 + mi*16 + lk*4;
      #pragma unroll
      for (int r=0;r<4;r++){
        Q[(size_t)(rowb + r)*N + col] = f2bu(acc[mi][ni][r] + bv);
      }
    }
  }
}

// ---------------- per-token head-attention (bf16 qkv input; round-4/5 verified) ----------------
__device__ inline void load16fb(const u16* p, float* f){
  uint4 a = ((const uint4*)p)[0], b4 = ((const uint4*)p)[1];
  f[0]=bl(a.x);  f[1]=bh(a.x);  f[2]=bl(a.y);  f[3]=bh(a.y);
  f[4]=bl(a.z);  f[5]=bh(a.z);  f[6]=bl(a.w);  f[7]=bh(a.w);
  f[8]=bl(b4.x); f[9]=bh(b4.x); f[10]=bl(b4.y);f[11]=bh(b4.y);
  f[12]=bl(b4.z);f[13]=bh(b4.z);f[14]=bl(b4.w);f[15]=bh(b4.w);
}

// 1 wave per token; lane = h*4 + dq; dq owns d in [dq*16, dq*16+16).
__global__ __launch_bounds__(256) void k_attn(const u16* __restrict__ Qkv,
                                              float* __restrict__ out){
  __shared__ __align__(16) u16 sm[4][3072];
  int w = threadIdx.x>>6, lane = threadIdx.x&63;
  int token = blockIdx.x*4 + w;
  const uint4* src = (const uint4*)(Qkv + (size_t)token*3072);
  uint4* dst = (uint4*)&sm[w][0];
  for (int i = lane; i < 384; i += 64) dst[i] = src[i];
  __syncthreads();

  int h = lane>>2, dq = lane&3;
  const u16* base = &sm[w][0];
  float qf[16];
  load16fb(base + h*192 + dq*16, qf);

  const float scale = 0.07216878364870323f;  // 1/sqrt(192)
  float s[16];
  #pragma unroll
  for (int g=0; g<16; ++g){
    float kf[16];
    load16fb(base + g*192 + 64 + dq*16, kf);
    float a = 0.f;
    #pragma unroll
    for (int j=0;j<16;j++) a += qf[j]*kf[j];
    a += __shfl_xor(a, 1);
    a += __shfl_xor(a, 2);
    s[g] = a * scale;
  }
  float mx = s[0];
  #pragma unroll
  for (int g=1; g<16; ++g) mx = fmaxf(mx, s[g]);
  float sum = 0.f;
  #pragma unroll
  for (int g=0; g<16; ++g){ s[g] = __expf(s[g]-mx); sum += s[g]; }
  float inv = 1.f/sum;

  float o[16];
  #pragma unroll
  for (int j=0;j<16;j++) o[j] = 0.f;
  #pragma unroll
  for (int g=0; g<16; ++g){
    float wg = s[g]*inv;
    float vf[16];
    load16fb(base + g*192 + 128 + dq*16, vf);
    #pragma unroll
    for (int j=0;j<16;j++) o[j] += wg*vf[j];
  }
  float* op = out + (size_t)token*1024 + h*64 + dq*16;
  #pragma unroll
  for (int i=0;i<4;i++)
    ((float4*)op)[i] = make_float4(o[i*4], o[i*4+1], o[i*4+2], o[i*4+3]);
}

// ---------------- fallback (ws too small): fully fused, f32 VALU, slow but correct ----------------
__global__ __launch_bounds__(256) void k_fallback(const float* __restrict__ X,
                                                  const float* __restrict__ W,
                                                  const float* __restrict__ bias,
                                                  float* __restrict__ out){
  int token = blockIdx.x;
  __shared__ float xs[1024];
  __shared__ float qkvs[3072];
  __shared__ float ss[16][16];
  __shared__ float ww[16][16];
  for (int i=threadIdx.x; i<1024; i+=256) xs[i] = X[(size_t)token*1024 + i];
  __syncthreads();
  for (int n=threadIdx.x; n<3072; n+=256){
    float acc = bias[n];
    for (int k=0;k<1024;k++) acc += xs[k]*W[(size_t)k*3072 + n];
    qkvs[n] = acc;
  }
  __syncthreads();
  {
    int t = threadIdx.x, h = t>>4, g = t&15;
    float a = 0.f;
    for (int d=0; d<64; d++) a += qkvs[h*192 + d]*qkvs[g*192 + 64 + d];
    ss[h][g] = a * 0.07216878364870323f;
  }
  __syncthreads();
  if (threadIdx.x < 16){
    int hh = threadIdx.x;
    float m = -1e30f;
    for (int g=0;g<16;g++) m = fmaxf(m, ss[hh][g]);
    float sum = 0.f;
    for (int g=0;g<16;g++){ float e = __expf(ss[hh][g]-m); ww[hh][g]=e; sum+=e; }
    float inv = 1.f/sum;
    for (int g=0;g<16;g++) ww[hh][g] *= inv;
  }
  __syncthreads();
  for (int i=threadIdx.x; i<1024; i+=256){
    int h = i>>6, d = i&63;
    float a = 0.f;
    for (int g=0;g<16;g++) a += ww[h][g]*qkvs[g*192 + 128 + d];
    out[(size_t)token*1024 + i] = a;
  }
}

extern "C" void kernel_launch(void* const* d_in, const int* in_sizes, int n_in,
                              void* d_out, int out_size, void* d_ws, size_t ws_size,
                              hipStream_t stream){
  const float* x    = (const float*)d_in[0];   // [4,4096,1024] f32
  const float* wk   = (const float*)d_in[1];   // [1024,16,192] f32
  const float* bias = (const float*)d_in[2];   // [16,192] f32
  float* out = (float*)d_out;                  // [4,4096,16,64] f32

  const size_t offW = 33554432;                       // Xb: 16M bf16
  const size_t offQ = offW + 6291456;                 // Wt: 3M bf16
  const size_t need = offQ + (size_t)16384*3072*2;    // Q bf16

  if (ws_size >= need){
    u16* Xb = (u16*)d_ws;
    u16* Wt = (u16*)((char*)d_ws + offW);
    u16* Q  = (u16*)((char*)d_ws + offQ);
    k_conv_x <<<2048, 256, 0, stream>>>(x, Xb, 16777216/4);
    k_conv_wt<<<dim3(96,32), 256, 0, stream>>>(wk, Wt);
    k_gemm   <<<3072, 256, 0, stream>>>(Xb, Wt, bias, Q);
    k_attn   <<<4096, 256, 0, stream>>>(Q, out);
  } else {
    k_fallback<<<16384, 256, 0, stream>>>(x, wk, bias, out);
  }
}

// Round 8
// 203.093 us; speedup vs baseline: 1.3568x; 1.0169x over previous
//
#include <hip/hip_runtime.h>
#include <cstdint>
#include <cstddef>

typedef unsigned short u16;
typedef __attribute__((ext_vector_type(8))) short bf16x8;
typedef __attribute__((ext_vector_type(4))) float f32x4;

__device__ inline float bl(uint32_t u){ union{float f;uint32_t i;}c; c.i = u<<16; return c.f; }
__device__ inline float bh(uint32_t u){ union{float f;uint32_t i;}c; c.i = u & 0xFFFF0000u; return c.f; }
__device__ inline u16 f2bu(float f){
  union{float f;uint32_t u;} c; c.f=f;
  uint32_t u=c.u;
  return (u16)((u + 0x7FFFu + ((u>>16)&1u))>>16);  // RNE
}

#define GLOAD_LDS16(g, l) __builtin_amdgcn_global_load_lds( \
    (__attribute__((address_space(1))) void*)(g), \
    (__attribute__((address_space(3))) void*)(l), 16, 0, 0)
#define BAR() do{ asm volatile("" ::: "memory"); __builtin_amdgcn_s_barrier(); asm volatile("" ::: "memory"); }while(0)
#define WAIT_LGKM0() do{ asm volatile("s_waitcnt lgkmcnt(0)" ::: "memory"); __builtin_amdgcn_sched_barrier(0); }while(0)

// ---------------- convert x: f32 -> bf16 ----------------
__global__ __launch_bounds__(256) void k_conv_x(const float* __restrict__ X,
                                                u16* __restrict__ Xb, int n4){
  int i = blockIdx.x*256 + threadIdx.x;
  int stride = gridDim.x*256;
  for (; i < n4; i += stride){
    float4 v = ((const float4*)X)[i];
    ushort4 o;
    o.x=f2bu(v.x); o.y=f2bu(v.y); o.z=f2bu(v.z); o.w=f2bu(v.w);
    ((ushort4*)Xb)[i] = o;
  }
}

// ---------------- transpose+convert W: [1024][3072] f32 -> [3072][1024] bf16 ----------------
__global__ __launch_bounds__(256) void k_conv_wt(const float* __restrict__ W,
                                                 u16* __restrict__ Wt){
  __shared__ float t[32][33];
  int n0 = blockIdx.x*32, k0 = blockIdx.y*32;
  int tx = threadIdx.x & 31, ty = threadIdx.x >> 5;
  #pragma unroll
  for (int i=0;i<32;i+=8)
    t[ty+i][tx] = W[(size_t)(k0+ty+i)*3072 + n0+tx];
  __syncthreads();
  #pragma unroll
  for (int i=0;i<32;i+=8)
    Wt[(size_t)(n0+ty+i)*1024 + k0+tx] = f2bu(t[tx][ty+i]);
}

// ---------------- GEMM: Qkv[16384][3072] = Xb[M][K]*Wt[N][K]^T + bias, bf16 out ----------------
// 256x256 tile, BK=32, 8 waves (2Mx4N), 4-deep LDS pipeline (128KB, prefetch distance 3 tiles
// ~= 960cy > 900cy HBM latency), counted vmcnt(8) once per K-tile, setprio around MFMA,
// XOR-swizzled LDS (T2: inverse-swizzled global source + swizzled read, linear gload_lds dest).
// Round-5 lesson respected: staging stays row-major coalesced (4 lanes x 64B per row).
__global__ __launch_bounds__(512, 2) void k_gemm2(const u16* __restrict__ Xb,
                                                  const u16* __restrict__ Wt,
                                                  const float* __restrict__ bias,
                                                  u16* __restrict__ Q){
  __shared__ __align__(16) u16 L[65536];   // [buf4][A01,B01 halves: 4][4096 u16] = 128 KiB
  const int K = 1024, N = 3072, NT = 32;
  int b = blockIdx.x;
  // XCD swizzle: nwg=768, 768%8==0 -> bijective
  int swz = (b & 7)*96 + (b >> 3);
  int bm = swz / 12, bn = swz % 12;
  int m0 = bm*256, n0 = bn*256;
  int tid = threadIdx.x, w = tid>>6, lane = tid&63, lr = lane&15, lk = lane>>4;
  int wm = w>>2, wn = w&3;

  f32x4 acc[8][4];
  #pragma unroll
  for (int i=0;i<8;i++)
    #pragma unroll
    for (int j=0;j<4;j++)
      acc[i][j] = (f32x4){0.f,0.f,0.f,0.f};

  // ---- staging source (inverse-swizzled): thread tid covers linear LDS bytes [tid*16,+16)
  // of one half-buffer; logical byte q = p ^ ((p>>7&1)<<4) ^ ((p>>8&1)<<5).
  int grow = tid>>2;
  int gcol = ((((tid&3)*16) ^ (((tid>>3)&1)<<4) ^ (((tid>>4)&1)<<5)) >> 1);
  const u16* gA0 = Xb + (size_t)(m0 + grow)*K + gcol;
  const u16* gA1 = Xb + (size_t)(m0 + 128 + grow)*K + gcol;
  const u16* gB0 = Wt + (size_t)(n0 + grow)*K + gcol;
  const u16* gB1 = Wt + (size_t)(n0 + 128 + grow)*K + gcol;

  // stage one K-tile j into buffer j&3 (order A-h0, A-h1, B-h0, B-h1 = 4 loads; vmcnt counts this)
#define STG_A(j) do{ int bf=(j)&3, kof=(j)*32; \
    GLOAD_LDS16(gA0+kof, &L[((bf*4+0)<<12) + tid*8]); \
    GLOAD_LDS16(gA1+kof, &L[((bf*4+1)<<12) + tid*8]); }while(0)
#define STG_B(j) do{ int bf=(j)&3, kof=(j)*32; \
    GLOAD_LDS16(gB0+kof, &L[((bf*4+2)<<12) + tid*8]); \
    GLOAD_LDS16(gB1+kof, &L[((bf*4+3)<<12) + tid*8]); }while(0)

  // ---- read-side swizzled addressing
  const char* Lb = (const char*)L;
  int colx = (lk*16) ^ (((lr>>1)&3)*16);      // col-bytes ^ swizzle(row bits 1,2 = lr bits 1,2)
  int arow = lr*64 + colx;                     // + mi*1024 per 16-row tile
  int brow = ((wn&1)*64 + lr)*64 + colx;       // + ni*1024

  // prologue: stage tiles 0,1,2 (12 loads), wait tile 0 landed (allow 8 in flight)
  STG_A(0); STG_B(0);
  STG_A(1); STG_B(1);
  STG_A(2); STG_B(2);
  asm volatile("s_waitcnt vmcnt(8)" ::: "memory");
  __builtin_amdgcn_sched_barrier(0);
  BAR();

  for (int t = 0; t < NT; ++t){
    int buf = t & 3;
    int Abase = (buf*4 + wm) << 13;            // bytes
    int Bbase = (buf*4 + 2 + (wn>>1)) << 13;
    bool st = (t <= NT-4);

    // ---- phase A: read A mi0-3 + all B, stage next A halves, 16 MFMA (rows 0-3)
    bf16x8 af0, af1, af2, af3, bf0, bf1, bf2, bf3;
    af0 = *(const bf16x8*)(Lb + Abase + 0*1024 + arow);
    af1 = *(const bf16x8*)(Lb + Abase + 1*1024 + arow);
    af2 = *(const bf16x8*)(Lb + Abase + 2*1024 + arow);
    af3 = *(const bf16x8*)(Lb + Abase + 3*1024 + arow);
    bf0 = *(const bf16x8*)(Lb + Bbase + 0*1024 + brow);
    bf1 = *(const bf16x8*)(Lb + Bbase + 1*1024 + brow);
    bf2 = *(const bf16x8*)(Lb + Bbase + 2*1024 + brow);
    bf3 = *(const bf16x8*)(Lb + Bbase + 3*1024 + brow);
    if (st) STG_A(t+3);
    BAR();
    WAIT_LGKM0();
    __builtin_amdgcn_s_setprio(1);
    acc[0][0] = __builtin_amdgcn_mfma_f32_16x16x32_bf16(af0, bf0, acc[0][0], 0,0,0);
    acc[0][1] = __builtin_amdgcn_mfma_f32_16x16x32_bf16(af0, bf1, acc[0][1], 0,0,0);
    acc[0][2] = __builtin_amdgcn_mfma_f32_16x16x32_bf16(af0, bf2, acc[0][2], 0,0,0);
    acc[0][3] = __builtin_amdgcn_mfma_f32_16x16x32_bf16(af0, bf3, acc[0][3], 0,0,0);
    acc[1][0] = __builtin_amdgcn_mfma_f32_16x16x32_bf16(af1, bf0, acc[1][0], 0,0,0);
    acc[1][1] = __builtin_amdgcn_mfma_f32_16x16x32_bf16(af1, bf1, acc[1][1], 0,0,0);
    acc[1][2] = __builtin_amdgcn_mfma_f32_16x16x32_bf16(af1, bf2, acc[1][2], 0,0,0);
    acc[1][3] = __builtin_amdgcn_mfma_f32_16x16x32_bf16(af1, bf3, acc[1][3], 0,0,0);
    acc[2][0] = __builtin_amdgcn_mfma_f32_16x16x32_bf16(af2, bf0, acc[2][0], 0,0,0);
    acc[2][1] = __builtin_amdgcn_mfma_f32_16x16x32_bf16(af2, bf1, acc[2][1], 0,0,0);
    acc[2][2] = __builtin_amdgcn_mfma_f32_16x16x32_bf16(af2, bf2, acc[2][2], 0,0,0);
    acc[2][3] = __builtin_amdgcn_mfma_f32_16x16x32_bf16(af2, bf3, acc[2][3], 0,0,0);
    acc[3][0] = __builtin_amdgcn_mfma_f32_16x16x32_bf16(af3, bf0, acc[3][0], 0,0,0);
    acc[3][1] = __builtin_amdgcn_mfma_f32_16x16x32_bf16(af3, bf1, acc[3][1], 0,0,0);
    acc[3][2] = __builtin_amdgcn_mfma_f32_16x16x32_bf16(af3, bf2, acc[3][2], 0,0,0);
    acc[3][3] = __builtin_amdgcn_mfma_f32_16x16x32_bf16(af3, bf3, acc[3][3], 0,0,0);
    __builtin_amdgcn_s_setprio(0);
    BAR();

    // ---- phase B: read A mi4-7 (B reused in regs), stage next B halves, 16 MFMA (rows 4-7)
    af0 = *(const bf16x8*)(Lb + Abase + 4*1024 + arow);
    af1 = *(const bf16x8*)(Lb + Abase + 5*1024 + arow);
    af2 = *(const bf16x8*)(Lb + Abase + 6*1024 + arow);
    af3 = *(const bf16x8*)(Lb + Abase + 7*1024 + arow);
    if (st) STG_B(t+3);
    BAR();
    WAIT_LGKM0();
    __builtin_amdgcn_s_setprio(1);
    acc[4][0] = __builtin_amdgcn_mfma_f32_16x16x32_bf16(af0, bf0, acc[4][0], 0,0,0);
    acc[4][1] = __builtin_amdgcn_mfma_f32_16x16x32_bf16(af0, bf1, acc[4][1], 0,0,0);
    acc[4][2] = __builtin_amdgcn_mfma_f32_16x16x32_bf16(af0, bf2, acc[4][2], 0,0,0);
    acc[4][3] = __builtin_amdgcn_mfma_f32_16x16x32_bf16(af0, bf3, acc[4][3], 0,0,0);
    acc[5][0] = __builtin_amdgcn_mfma_f32_16x16x32_bf16(af1, bf0, acc[5][0], 0,0,0);
    acc[5][1] = __builtin_amdgcn_mfma_f32_16x16x32_bf16(af1, bf1, acc[5][1], 0,0,0);
    acc[5][2] = __builtin_amdgcn_mfma_f32_16x16x32_bf16(af1, bf2, acc[5][2], 0,0,0);
    acc[5][3] = __builtin_amdgcn_mfma_f32_16x16x32_bf16(af1, bf3, acc[5][3], 0,0,0);
    acc[6][0] = __builtin_amdgcn_mfma_f32_16x16x32_bf16(af2, bf0, acc[6][0], 0,0,0);
    acc[6][1] = __builtin_amdgcn_mfma_f32_16x16x32_bf16(af2, bf1, acc[6][1], 0,0,0);
    acc[6][2] = __builtin_amdgcn_mfma_f32_16x16x32_bf16(af2, bf2, acc[6][2], 0,0,0);
    acc[6][3] = __builtin_amdgcn_mfma_f32_16x16x32_bf16(af2, bf3, acc[6][3], 0,0,0);
    acc[7][0] = __builtin_amdgcn_mfma_f32_16x16x32_bf16(af3, bf0, acc[7][0], 0,0,0);
    acc[7][1] = __builtin_amdgcn_mfma_f32_16x16x32_bf16(af3, bf1, acc[7][1], 0,0,0);
    acc[7][2] = __builtin_amdgcn_mfma_f32_16x16x32_bf16(af3, bf2, acc[7][2], 0,0,0);
    acc[7][3] = __builtin_amdgcn_mfma_f32_16x16x32_bf16(af3, bf3, acc[7][3], 0,0,0);
    __builtin_amdgcn_s_setprio(0);
    // counted wait: ensure tile t+1 landed; allow 8 (last 2 tiles' stages) in flight
    if (t <= NT-4)      { asm volatile("s_waitcnt vmcnt(8)" ::: "memory"); }
    else if (t == NT-3) { asm volatile("s_waitcnt vmcnt(4)" ::: "memory"); }
    else if (t == NT-2) { asm volatile("s_waitcnt vmcnt(0)" ::: "memory"); }
    __builtin_amdgcn_sched_barrier(0);
    BAR();
  }
#undef STG_A
#undef STG_B

  // epilogue: C/D layout col=lane&15, row=(lane>>4)*4+reg  [m89-verified, round-3/7 mapping]
  #pragma unroll
  for (int ni=0; ni<4; ++ni){
    int col = n0 + wn*64 + ni*16 + lr;
    float bv = bias[col];
    #pragma unroll
    for (int mi=0; mi<8; ++mi){
      int rowb = m0 + wm*128 + mi*16 + lk*4;
      #pragma unroll
      for (int r=0;r<4;r++){
        Q[(size_t)(rowb + r)*N + col] = f2bu(acc[mi][ni][r] + bv);
      }
    }
  }
}

// ---------------- per-token head-attention (bf16 qkv input; round-4/7 verified) ----------------
__device__ inline void load16fb(const u16* p, float* f){
  uint4 a = ((const uint4*)p)[0], b4 = ((const uint4*)p)[1];
  f[0]=bl(a.x);  f[1]=bh(a.x);  f[2]=bl(a.y);  f[3]=bh(a.y);
  f[4]=bl(a.z);  f[5]=bh(a.z);  f[6]=bl(a.w);  f[7]=bh(a.w);
  f[8]=bl(b4.x); f[9]=bh(b4.x); f[10]=bl(b4.y);f[11]=bh(b4.y);
  f[12]=bl(b4.z);f[13]=bh(b4.z);f[14]=bl(b4.w);f[15]=bh(b4.w);
}

// 1 wave per token; lane = h*4 + dq; dq owns d in [dq*16, dq*16+16).
__global__ __launch_bounds__(256) void k_attn(const u16* __restrict__ Qkv,
                                              float* __restrict__ out){
  __shared__ __align__(16) u16 sm[4][3072];
  int w = threadIdx.x>>6, lane = threadIdx.x&63;
  int token = blockIdx.x*4 + w;
  const uint4* src = (const uint4*)(Qkv + (size_t)token*3072);
  uint4* dst = (uint4*)&sm[w][0];
  for (int i = lane; i < 384; i += 64) dst[i] = src[i];
  __syncthreads();

  int h = lane>>2, dq = lane&3;
  const u16* base = &sm[w][0];
  float qf[16];
  load16fb(base + h*192 + dq*16, qf);

  const float scale = 0.07216878364870323f;  // 1/sqrt(192)
  float s[16];
  #pragma unroll
  for (int g=0; g<16; ++g){
    float kf[16];
    load16fb(base + g*192 + 64 + dq*16, kf);
    float a = 0.f;
    #pragma unroll
    for (int j=0;j<16;j++) a += qf[j]*kf[j];
    a += __shfl_xor(a, 1);
    a += __shfl_xor(a, 2);
    s[g] = a * scale;
  }
  float mx = s[0];
  #pragma unroll
  for (int g=1; g<16; ++g) mx = fmaxf(mx, s[g]);
  float sum = 0.f;
  #pragma unroll
  for (int g=0; g<16; ++g){ s[g] = __expf(s[g]-mx); sum += s[g]; }
  float inv = 1.f/sum;

  float o[16];
  #pragma unroll
  for (int j=0;j<16;j++) o[j] = 0.f;
  #pragma unroll
  for (int g=0; g<16; ++g){
    float wg = s[g]*inv;
    float vf[16];
    load16fb(base + g*192 + 128 + dq*16, vf);
    #pragma unroll
    for (int j=0;j<16;j++) o[j] += wg*vf[j];
  }
  float* op = out + (size_t)token*1024 + h*64 + dq*16;
  #pragma unroll
  for (int i=0;i<4;i++)
    ((float4*)op)[i] = make_float4(o[i*4], o[i*4+1], o[i*4+2], o[i*4+3]);
}

// ---------------- fallback (ws too small): fully fused, f32 VALU, slow but correct ----------------
__global__ __launch_bounds__(256) void k_fallback(const float* __restrict__ X,
                                                  const float* __restrict__ W,
                                                  const float* __restrict__ bias,
                                                  float* __restrict__ out){
  int token = blockIdx.x;
  __shared__ float xs[1024];
  __shared__ float qkvs[3072];
  __shared__ float ss[16][16];
  __shared__ float ww[16][16];
  for (int i=threadIdx.x; i<1024; i+=256) xs[i] = X[(size_t)token*1024 + i];
  __syncthreads();
  for (int n=threadIdx.x; n<3072; n+=256){
    float acc = bias[n];
    for (int k=0;k<1024;k++) acc += xs[k]*W[(size_t)k*3072 + n];
    qkvs[n] = acc;
  }
  __syncthreads();
  {
    int t = threadIdx.x, h = t>>4, g = t&15;
    float a = 0.f;
    for (int d=0; d<64; d++) a += qkvs[h*192 + d]*qkvs[g*192 + 64 + d];
    ss[h][g] = a * 0.07216878364870323f;
  }
  __syncthreads();
  if (threadIdx.x < 16){
    int hh = threadIdx.x;
    float m = -1e30f;
    for (int g=0;g<16;g++) m = fmaxf(m, ss[hh][g]);
    float sum = 0.f;
    for (int g=0;g<16;g++){ float e = __expf(ss[hh][g]-m); ww[hh][g]=e; sum+=e; }
    float inv = 1.f/sum;
    for (int g=0;g<16;g++) ww[hh][g] *= inv;
  }
  __syncthreads();
  for (int i=threadIdx.x; i<1024; i+=256){
    int h = i>>6, d = i&63;
    float a = 0.f;
    for (int g=0;g<16;g++) a += ww[h][g]*qkvs[g*192 + 128 + d];
    out[(size_t)token*1024 + i] = a;
  }
}

extern "C" void kernel_launch(void* const* d_in, const int* in_sizes, int n_in,
                              void* d_out, int out_size, void* d_ws, size_t ws_size,
                              hipStream_t stream){
  const float* x    = (const float*)d_in[0];   // [4,4096,1024] f32
  const float* wk   = (const float*)d_in[1];   // [1024,16,192] f32
  const float* bias = (const float*)d_in[2];   // [16,192] f32
  float* out = (float*)d_out;                  // [4,4096,16,64] f32

  const size_t offW = 33554432;                       // Xb: 16M bf16
  const size_t offQ = offW + 6291456;                 // Wt: 3M bf16
  const size_t need = offQ + (size_t)16384*3072*2;    // Q bf16

  if (ws_size >= need){
    u16* Xb = (u16*)d_ws;
    u16* Wt = (u16*)((char*)d_ws + offW);
    u16* Q  = (u16*)((char*)d_ws + offQ);
    k_conv_x <<<2048, 256, 0, stream>>>(x, Xb, 16777216/4);
    k_conv_wt<<<dim3(96,32), 256, 0, stream>>>(wk, Wt);
    k_gemm2  <<<768, 512, 0, stream>>>(Xb, Wt, bias, Q);
    k_attn   <<<4096, 256, 0, stream>>>(Q, out);
  } else {
    k_fallback<<<16384, 256, 0, stream>>>(x, wk, bias, out);
  }
}

// Round 9
// 198.113 us; speedup vs baseline: 1.3909x; 1.0251x over previous
//
#include <hip/hip_runtime.h>
#include <cstdint>
#include <cstddef>

typedef unsigned short u16;
typedef __attribute__((ext_vector_type(8))) short bf16x8;
typedef __attribute__((ext_vector_type(4))) float f32x4;

__device__ inline float bl(uint32_t u){ union{float f;uint32_t i;}c; c.i = u<<16; return c.f; }
__device__ inline float bh(uint32_t u){ union{float f;uint32_t i;}c; c.i = u & 0xFFFF0000u; return c.f; }
__device__ inline u16 f2bu(float f){
  union{float f;uint32_t u;} c; c.f=f;
  uint32_t u=c.u;
  return (u16)((u + 0x7FFFu + ((u>>16)&1u))>>16);  // RNE
}

#define GLOAD_LDS16(g, l) __builtin_amdgcn_global_load_lds( \
    (__attribute__((address_space(1))) void*)(g), \
    (__attribute__((address_space(3))) void*)(l), 16, 0, 0)
#define BAR() do{ asm volatile("" ::: "memory"); __builtin_amdgcn_s_barrier(); asm volatile("" ::: "memory"); }while(0)
#define WAIT_LGKM0() do{ asm volatile("s_waitcnt lgkmcnt(0)" ::: "memory"); __builtin_amdgcn_sched_barrier(0); }while(0)

// ---------------- convert x: f32 -> bf16 ----------------
__global__ __launch_bounds__(256) void k_conv_x(const float* __restrict__ X,
                                                u16* __restrict__ Xb, int n4){
  int i = blockIdx.x*256 + threadIdx.x;
  int stride = gridDim.x*256;
  for (; i < n4; i += stride){
    float4 v = ((const float4*)X)[i];
    ushort4 o;
    o.x=f2bu(v.x); o.y=f2bu(v.y); o.z=f2bu(v.z); o.w=f2bu(v.w);
    ((ushort4*)Xb)[i] = o;
  }
}

// ---------------- transpose+convert W: [1024][3072] f32 -> [3072][1024] bf16 ----------------
__global__ __launch_bounds__(256) void k_conv_wt(const float* __restrict__ W,
                                                 u16* __restrict__ Wt){
  __shared__ float t[32][33];
  int n0 = blockIdx.x*32, k0 = blockIdx.y*32;
  int tx = threadIdx.x & 31, ty = threadIdx.x >> 5;
  #pragma unroll
  for (int i=0;i<32;i+=8)
    t[ty+i][tx] = W[(size_t)(k0+ty+i)*3072 + n0+tx];
  __syncthreads();
  #pragma unroll
  for (int i=0;i<32;i+=8)
    Wt[(size_t)(n0+ty+i)*1024 + k0+tx] = f2bu(t[tx][ty+i]);
}

// ---------------- GEMM: Qkv[16384][3072] = Xb[M][K]*Wt[N][K]^T + bias, bf16 out ----------------
// Round-8 pipeline (verified: 0 bank conflicts, FETCH 94MB): 256x256 tile, BK=32, 8 waves,
// 4-deep LDS pipeline, counted vmcnt(8), setprio, XOR-swizzled reads, coalesced staging.
// Round-9 change: LDS-staged coalesced epilogue (512B row-runs) to kill the measured ~1.9x
// HBM write amplification (WRITE_SIZE 185-192MB vs ideal ~100MB).
__global__ __launch_bounds__(512, 2) void k_gemm2(const u16* __restrict__ Xb,
                                                  const u16* __restrict__ Wt,
                                                  const float* __restrict__ bias,
                                                  u16* __restrict__ Q){
  __shared__ __align__(16) u16 L[65536];   // K-loop: [buf4][A01,B01: 4][4096 u16]; epilogue: 256x256 C-tile
  const int K = 1024, N = 3072, NT = 32;
  int b = blockIdx.x;
  // XCD swizzle: nwg=768, 768%8==0 -> bijective
  int swz = (b & 7)*96 + (b >> 3);
  int bm = swz / 12, bn = swz % 12;
  int m0 = bm*256, n0 = bn*256;
  int tid = threadIdx.x, w = tid>>6, lane = tid&63, lr = lane&15, lk = lane>>4;
  int wm = w>>2, wn = w&3;

  f32x4 acc[8][4];
  #pragma unroll
  for (int i=0;i<8;i++)
    #pragma unroll
    for (int j=0;j<4;j++)
      acc[i][j] = (f32x4){0.f,0.f,0.f,0.f};

  // ---- staging source (inverse-swizzled): thread tid covers linear LDS bytes [tid*16,+16)
  int grow = tid>>2;
  int gcol = ((((tid&3)*16) ^ (((tid>>3)&1)<<4) ^ (((tid>>4)&1)<<5)) >> 1);
  const u16* gA0 = Xb + (size_t)(m0 + grow)*K + gcol;
  const u16* gA1 = Xb + (size_t)(m0 + 128 + grow)*K + gcol;
  const u16* gB0 = Wt + (size_t)(n0 + grow)*K + gcol;
  const u16* gB1 = Wt + (size_t)(n0 + 128 + grow)*K + gcol;

#define STG_A(j) do{ int bf=(j)&3, kof=(j)*32; \
    GLOAD_LDS16(gA0+kof, &L[((bf*4+0)<<12) + tid*8]); \
    GLOAD_LDS16(gA1+kof, &L[((bf*4+1)<<12) + tid*8]); }while(0)
#define STG_B(j) do{ int bf=(j)&3, kof=(j)*32; \
    GLOAD_LDS16(gB0+kof, &L[((bf*4+2)<<12) + tid*8]); \
    GLOAD_LDS16(gB1+kof, &L[((bf*4+3)<<12) + tid*8]); }while(0)

  // ---- read-side swizzled addressing
  const char* Lb = (const char*)L;
  int colx = (lk*16) ^ (((lr>>1)&3)*16);
  int arow = lr*64 + colx;
  int brow = ((wn&1)*64 + lr)*64 + colx;

  // prologue: stage tiles 0,1,2 (12 loads), wait tile 0 landed
  STG_A(0); STG_B(0);
  STG_A(1); STG_B(1);
  STG_A(2); STG_B(2);
  asm volatile("s_waitcnt vmcnt(8)" ::: "memory");
  __builtin_amdgcn_sched_barrier(0);
  BAR();

  for (int t = 0; t < NT; ++t){
    int buf = t & 3;
    int Abase = (buf*4 + wm) << 13;
    int Bbase = (buf*4 + 2 + (wn>>1)) << 13;
    bool st = (t <= NT-4);

    // ---- phase A
    bf16x8 af0, af1, af2, af3, bf0, bf1, bf2, bf3;
    af0 = *(const bf16x8*)(Lb + Abase + 0*1024 + arow);
    af1 = *(const bf16x8*)(Lb + Abase + 1*1024 + arow);
    af2 = *(const bf16x8*)(Lb + Abase + 2*1024 + arow);
    af3 = *(const bf16x8*)(Lb + Abase + 3*1024 + arow);
    bf0 = *(const bf16x8*)(Lb + Bbase + 0*1024 + brow);
    bf1 = *(const bf16x8*)(Lb + Bbase + 1*1024 + brow);
    bf2 = *(const bf16x8*)(Lb + Bbase + 2*1024 + brow);
    bf3 = *(const bf16x8*)(Lb + Bbase + 3*1024 + brow);
    if (st) STG_A(t+3);
    BAR();
    WAIT_LGKM0();
    __builtin_amdgcn_s_setprio(1);
    acc[0][0] = __builtin_amdgcn_mfma_f32_16x16x32_bf16(af0, bf0, acc[0][0], 0,0,0);
    acc[0][1] = __builtin_amdgcn_mfma_f32_16x16x32_bf16(af0, bf1, acc[0][1], 0,0,0);
    acc[0][2] = __builtin_amdgcn_mfma_f32_16x16x32_bf16(af0, bf2, acc[0][2], 0,0,0);
    acc[0][3] = __builtin_amdgcn_mfma_f32_16x16x32_bf16(af0, bf3, acc[0][3], 0,0,0);
    acc[1][0] = __builtin_amdgcn_mfma_f32_16x16x32_bf16(af1, bf0, acc[1][0], 0,0,0);
    acc[1][1] = __builtin_amdgcn_mfma_f32_16x16x32_bf16(af1, bf1, acc[1][1], 0,0,0);
    acc[1][2] = __builtin_amdgcn_mfma_f32_16x16x32_bf16(af1, bf2, acc[1][2], 0,0,0);
    acc[1][3] = __builtin_amdgcn_mfma_f32_16x16x32_bf16(af1, bf3, acc[1][3], 0,0,0);
    acc[2][0] = __builtin_amdgcn_mfma_f32_16x16x32_bf16(af2, bf0, acc[2][0], 0,0,0);
    acc[2][1] = __builtin_amdgcn_mfma_f32_16x16x32_bf16(af2, bf1, acc[2][1], 0,0,0);
    acc[2][2] = __builtin_amdgcn_mfma_f32_16x16x32_bf16(af2, bf2, acc[2][2], 0,0,0);
    acc[2][3] = __builtin_amdgcn_mfma_f32_16x16x32_bf16(af2, bf3, acc[2][3], 0,0,0);
    acc[3][0] = __builtin_amdgcn_mfma_f32_16x16x32_bf16(af3, bf0, acc[3][0], 0,0,0);
    acc[3][1] = __builtin_amdgcn_mfma_f32_16x16x32_bf16(af3, bf1, acc[3][1], 0,0,0);
    acc[3][2] = __builtin_amdgcn_mfma_f32_16x16x32_bf16(af3, bf2, acc[3][2], 0,0,0);
    acc[3][3] = __builtin_amdgcn_mfma_f32_16x16x32_bf16(af3, bf3, acc[3][3], 0,0,0);
    __builtin_amdgcn_s_setprio(0);
    BAR();

    // ---- phase B
    af0 = *(const bf16x8*)(Lb + Abase + 4*1024 + arow);
    af1 = *(const bf16x8*)(Lb + Abase + 5*1024 + arow);
    af2 = *(const bf16x8*)(Lb + Abase + 6*1024 + arow);
    af3 = *(const bf16x8*)(Lb + Abase + 7*1024 + arow);
    if (st) STG_B(t+3);
    BAR();
    WAIT_LGKM0();
    __builtin_amdgcn_s_setprio(1);
    acc[4][0] = __builtin_amdgcn_mfma_f32_16x16x32_bf16(af0, bf0, acc[4][0], 0,0,0);
    acc[4][1] = __builtin_amdgcn_mfma_f32_16x16x32_bf16(af0, bf1, acc[4][1], 0,0,0);
    acc[4][2] = __builtin_amdgcn_mfma_f32_16x16x32_bf16(af0, bf2, acc[4][2], 0,0,0);
    acc[4][3] = __builtin_amdgcn_mfma_f32_16x16x32_bf16(af0, bf3, acc[4][3], 0,0,0);
    acc[5][0] = __builtin_amdgcn_mfma_f32_16x16x32_bf16(af1, bf0, acc[5][0], 0,0,0);
    acc[5][1] = __builtin_amdgcn_mfma_f32_16x16x32_bf16(af1, bf1, acc[5][1], 0,0,0);
    acc[5][2] = __builtin_amdgcn_mfma_f32_16x16x32_bf16(af1, bf2, acc[5][2], 0,0,0);
    acc[5][3] = __builtin_amdgcn_mfma_f32_16x16x32_bf16(af1, bf3, acc[5][3], 0,0,0);
    acc[6][0] = __builtin_amdgcn_mfma_f32_16x16x32_bf16(af2, bf0, acc[6][0], 0,0,0);
    acc[6][1] = __builtin_amdgcn_mfma_f32_16x16x32_bf16(af2, bf1, acc[6][1], 0,0,0);
    acc[6][2] = __builtin_amdgcn_mfma_f32_16x16x32_bf16(af2, bf2, acc[6][2], 0,0,0);
    acc[6][3] = __builtin_amdgcn_mfma_f32_16x16x32_bf16(af2, bf3, acc[6][3], 0,0,0);
    acc[7][0] = __builtin_amdgcn_mfma_f32_16x16x32_bf16(af3, bf0, acc[7][0], 0,0,0);
    acc[7][1] = __builtin_amdgcn_mfma_f32_16x16x32_bf16(af3, bf1, acc[7][1], 0,0,0);
    acc[7][2] = __builtin_amdgcn_mfma_f32_16x16x32_bf16(af3, bf2, acc[7][2], 0,0,0);
    acc[7][3] = __builtin_amdgcn_mfma_f32_16x16x32_bf16(af3, bf3, acc[7][3], 0,0,0);
    __builtin_amdgcn_s_setprio(0);
    if (t <= NT-4)      { asm volatile("s_waitcnt vmcnt(8)" ::: "memory"); }
    else if (t == NT-3) { asm volatile("s_waitcnt vmcnt(4)" ::: "memory"); }
    else if (t == NT-2) { asm volatile("s_waitcnt vmcnt(0)" ::: "memory"); }
    __builtin_amdgcn_sched_barrier(0);
    BAR();
  }
#undef STG_A
#undef STG_B

  // ---- epilogue: stage C-tile in LDS (per-wave [128][64] regions, XOR swizzle), then
  // fully-coalesced 512B-row global stores. Kills the measured write amplification.
  {
    u16* reg = &L[w*8192];
    #pragma unroll
    for (int nf=0; nf<4; ++nf){
      int col = nf*16 + lr;
      float bv = bias[n0 + wn*64 + col];
      #pragma unroll
      for (int mi=0; mi<8; ++mi){
        #pragma unroll
        for (int r=0;r<4;r++){
          int rr = mi*16 + lk*4 + r;
          reg[rr*64 + (col ^ ((rr&7)<<3))] = f2bu(acc[mi][nf][r] + bv);
        }
      }
    }
    BAR();
    // pass p: 16 rows; lanes: 32 threads per row cover 256 cols (512B contiguous)
    int co = (tid&31)*8;            // col 0..255, step 8
    int rgn_c = co>>6;              // col region 0..3
    int c6 = co&63;
    #pragma unroll
    for (int p=0; p<16; ++p){
      int rI = p*16 + (tid>>5);
      int wreg = ((rI>>7)<<2) + rgn_c;
      int rr = rI & 127;
      const u16* src = &L[wreg*8192 + rr*64 + (c6 ^ ((rr&7)<<3))];
      uint4 v = *(const uint4*)src;
      *(uint4*)&Q[(size_t)(m0+rI)*N + n0 + co] = v;
    }
  }
}

// ---------------- per-token head-attention (bf16 qkv input; round-4/7 verified) ----------------
__device__ inline void load16fb(const u16* p, float* f){
  uint4 a = ((const uint4*)p)[0], b4 = ((const uint4*)p)[1];
  f[0]=bl(a.x);  f[1]=bh(a.x);  f[2]=bl(a.y);  f[3]=bh(a.y);
  f[4]=bl(a.z);  f[5]=bh(a.z);  f[6]=bl(a.w);  f[7]=bh(a.w);
  f[8]=bl(b4.x); f[9]=bh(b4.x); f[10]=bl(b4.y);f[11]=bh(b4.y);
  f[12]=bl(b4.z);f[13]=bh(b4.z);f[14]=bl(b4.w);f[15]=bh(b4.w);
}

// 1 wave per token; lane = h*4 + dq; dq owns d in [dq*16, dq*16+16).
__global__ __launch_bounds__(256) void k_attn(const u16* __restrict__ Qkv,
                                              float* __restrict__ out){
  __shared__ __align__(16) u16 sm[4][3072];
  int w = threadIdx.x>>6, lane = threadIdx.x&63;
  int token = blockIdx.x*4 + w;
  const uint4* src = (const uint4*)(Qkv + (size_t)token*3072);
  uint4* dst = (uint4*)&sm[w][0];
  for (int i = lane; i < 384; i += 64) dst[i] = src[i];
  __syncthreads();

  int h = lane>>2, dq = lane&3;
  const u16* base = &sm[w][0];
  float qf[16];
  load16fb(base + h*192 + dq*16, qf);

  const float scale = 0.07216878364870323f;  // 1/sqrt(192)
  float s[16];
  #pragma unroll
  for (int g=0; g<16; ++g){
    float kf[16];
    load16fb(base + g*192 + 64 + dq*16, kf);
    float a = 0.f;
    #pragma unroll
    for (int j=0;j<16;j++) a += qf[j]*kf[j];
    a += __shfl_xor(a, 1);
    a += __shfl_xor(a, 2);
    s[g] = a * scale;
  }
  float mx = s[0];
  #pragma unroll
  for (int g=1; g<16; ++g) mx = fmaxf(mx, s[g]);
  float sum = 0.f;
  #pragma unroll
  for (int g=0; g<16; ++g){ s[g] = __expf(s[g]-mx); sum += s[g]; }
  float inv = 1.f/sum;

  float o[16];
  #pragma unroll
  for (int j=0;j<16;j++) o[j] = 0.f;
  #pragma unroll
  for (int g=0; g<16; ++g){
    float wg = s[g]*inv;
    float vf[16];
    load16fb(base + g*192 + 128 + dq*16, vf);
    #pragma unroll
    for (int j=0;j<16;j++) o[j] += wg*vf[j];
  }
  float* op = out + (size_t)token*1024 + h*64 + dq*16;
  #pragma unroll
  for (int i=0;i<4;i++)
    ((float4*)op)[i] = make_float4(o[i*4], o[i*4+1], o[i*4+2], o[i*4+3]);
}

// ---------------- fallback (ws too small): fully fused, f32 VALU, slow but correct ----------------
__global__ __launch_bounds__(256) void k_fallback(const float* __restrict__ X,
                                                  const float* __restrict__ W,
                                                  const float* __restrict__ bias,
                                                  float* __restrict__ out){
  int token = blockIdx.x;
  __shared__ float xs[1024];
  __shared__ float qkvs[3072];
  __shared__ float ss[16][16];
  __shared__ float ww[16][16];
  for (int i=threadIdx.x; i<1024; i+=256) xs[i] = X[(size_t)token*1024 + i];
  __syncthreads();
  for (int n=threadIdx.x; n<3072; n+=256){
    float acc = bias[n];
    for (int k=0;k<1024;k++) acc += xs[k]*W[(size_t)k*3072 + n];
    qkvs[n] = acc;
  }
  __syncthreads();
  {
    int t = threadIdx.x, h = t>>4, g = t&15;
    float a = 0.f;
    for (int d=0; d<64; d++) a += qkvs[h*192 + d]*qkvs[g*192 + 64 + d];
    ss[h][g] = a * 0.07216878364870323f;
  }
  __syncthreads();
  if (threadIdx.x < 16){
    int hh = threadIdx.x;
    float m = -1e30f;
    for (int g=0;g<16;g++) m = fmaxf(m, ss[hh][g]);
    float sum = 0.f;
    for (int g=0;g<16;g++){ float e = __expf(ss[hh][g]-m); ww[hh][g]=e; sum+=e; }
    float inv = 1.f/sum;
    for (int g=0;g<16;g++) ww[hh][g] *= inv;
  }
  __syncthreads();
  for (int i=threadIdx.x; i<1024; i+=256){
    int h = i>>6, d = i&63;
    float a = 0.f;
    for (int g=0;g<16;g++) a += ww[h][g]*qkvs[g*192 + 128 + d];
    out[(size_t)token*1024 + i] = a;
  }
}

extern "C" void kernel_launch(void* const* d_in, const int* in_sizes, int n_in,
                              void* d_out, int out_size, void* d_ws, size_t ws_size,
                              hipStream_t stream){
  const float* x    = (const float*)d_in[0];   // [4,4096,1024] f32
  const float* wk   = (const float*)d_in[1];   // [1024,16,192] f32
  const float* bias = (const float*)d_in[2];   // [16,192] f32
  float* out = (float*)d_out;                  // [4,4096,16,64] f32

  const size_t offW = 33554432;                       // Xb: 16M bf16
  const size_t offQ = offW + 6291456;                 // Wt: 3M bf16
  const size_t need = offQ + (size_t)16384*3072*2;    // Q bf16

  if (ws_size >= need){
    u16* Xb = (u16*)d_ws;
    u16* Wt = (u16*)((char*)d_ws + offW);
    u16* Q  = (u16*)((char*)d_ws + offQ);
    k_conv_x <<<2048, 256, 0, stream>>>(x, Xb, 16777216/4);
    k_conv_wt<<<dim3(96,32), 256, 0, stream>>>(wk, Wt);
    k_gemm2  <<<768, 512, 0, stream>>>(Xb, Wt, bias, Q);
    k_attn   <<<4096, 256, 0, stream>>>(Q, out);
  } else {
    k_fallback<<<16384, 256, 0, stream>>>(x, wk, bias, out);
  }
}

// Round 10
// 191.910 us; speedup vs baseline: 1.4359x; 1.0323x over previous
//
#include <hip/hip_runtime.h>
#include <cstdint>
#include <cstddef>

typedef unsigned short u16;
typedef __attribute__((ext_vector_type(8))) short bf16x8;
typedef __attribute__((ext_vector_type(4))) float f32x4;

__device__ inline float bl(uint32_t u){ union{float f;uint32_t i;}c; c.i = u<<16; return c.f; }
__device__ inline float bh(uint32_t u){ union{float f;uint32_t i;}c; c.i = u & 0xFFFF0000u; return c.f; }
__device__ inline u16 f2bu(float f){
  union{float f;uint32_t u;} c; c.f=f;
  uint32_t u=c.u;
  return (u16)((u + 0x7FFFu + ((u>>16)&1u))>>16);  // RNE
}

#define GLOAD_LDS16(g, l) __builtin_amdgcn_global_load_lds( \
    (__attribute__((address_space(1))) void*)(g), \
    (__attribute__((address_space(3))) void*)(l), 16, 0, 0)
#define BAR() do{ asm volatile("" ::: "memory"); __builtin_amdgcn_s_barrier(); asm volatile("" ::: "memory"); }while(0)

// ---------------- fused convert: X f32->bf16 (blocks 0..2047) + W transpose (blocks 2048..5119) --
__global__ __launch_bounds__(256) void k_conv(const float* __restrict__ X,
                                              u16* __restrict__ Xb,
                                              const float* __restrict__ W,
                                              u16* __restrict__ Wt){
  __shared__ float t[32][33];
  int b = blockIdx.x;
  if (b < 2048){
    int i = b*256 + threadIdx.x;
    for (; i < 4194304; i += 2048*256){
      float4 v = ((const float4*)X)[i];
      ushort4 o;
      o.x=f2bu(v.x); o.y=f2bu(v.y); o.z=f2bu(v.z); o.w=f2bu(v.w);
      ((ushort4*)Xb)[i] = o;
    }
  } else {
    int bb = b - 2048;                 // 0..3071
    int n0 = (bb % 96)*32, k0 = (bb / 96)*32;
    int tx = threadIdx.x & 31, ty = threadIdx.x >> 5;
    #pragma unroll
    for (int i=0;i<32;i+=8)
      t[ty+i][tx] = W[(size_t)(k0+ty+i)*3072 + n0+tx];
    __syncthreads();
    #pragma unroll
    for (int i=0;i<32;i+=8)
      Wt[(size_t)(n0+ty+i)*1024 + k0+tx] = f2bu(t[tx][ty+i]);
  }
}

// ---------------- GEMM: Qkv[16384][3072] = Xb[M][K]*Wt[N][K]^T + bias, bf16 out ----------------
// r9 verified dataflow: 256x256 tile, BK=32, 8 waves, 4-buf distance-3 prefetch, counted
// vmcnt(8), XOR-swizzled LDS (0 conflicts), coalesced staging, LDS-staged epilogue (WRITE=96MB).
// r10 change: ONE barrier per K-tile (drop mid-tile lockstep barriers + explicit lgkm drains);
// compiler interleaves 12 ds_reads + 32 MFMA, waves drift within the tile -> read/MFMA overlap.
__global__ __launch_bounds__(512, 2) void k_gemm2(const u16* __restrict__ Xb,
                                                  const u16* __restrict__ Wt,
                                                  const float* __restrict__ bias,
                                                  u16* __restrict__ Q){
  __shared__ __align__(16) u16 L[65536];   // K-loop: [buf4][A01,B01: 4][4096 u16]; epilogue: C-tile
  const int K = 1024, N = 3072, NT = 32;
  int b = blockIdx.x;
  // XCD swizzle: nwg=768, 768%8==0 -> bijective
  int swz = (b & 7)*96 + (b >> 3);
  int bm = swz / 12, bn = swz % 12;
  int m0 = bm*256, n0 = bn*256;
  int tid = threadIdx.x, w = tid>>6, lane = tid&63, lr = lane&15, lk = lane>>4;
  int wm = w>>2, wn = w&3;

  f32x4 acc[8][4];
  #pragma unroll
  for (int i=0;i<8;i++)
    #pragma unroll
    for (int j=0;j<4;j++)
      acc[i][j] = (f32x4){0.f,0.f,0.f,0.f};

  // ---- staging source (inverse-swizzled, r8/r9-verified)
  int grow = tid>>2;
  int gcol = ((((tid&3)*16) ^ (((tid>>3)&1)<<4) ^ (((tid>>4)&1)<<5)) >> 1);
  const u16* gA0 = Xb + (size_t)(m0 + grow)*K + gcol;
  const u16* gA1 = Xb + (size_t)(m0 + 128 + grow)*K + gcol;
  const u16* gB0 = Wt + (size_t)(n0 + grow)*K + gcol;
  const u16* gB1 = Wt + (size_t)(n0 + 128 + grow)*K + gcol;

#define STG_A(j) do{ int bf=(j)&3, kof=(j)*32; \
    GLOAD_LDS16(gA0+kof, &L[((bf*4+0)<<12) + tid*8]); \
    GLOAD_LDS16(gA1+kof, &L[((bf*4+1)<<12) + tid*8]); }while(0)
#define STG_B(j) do{ int bf=(j)&3, kof=(j)*32; \
    GLOAD_LDS16(gB0+kof, &L[((bf*4+2)<<12) + tid*8]); \
    GLOAD_LDS16(gB1+kof, &L[((bf*4+3)<<12) + tid*8]); }while(0)

  // ---- read-side swizzled addressing (r8/r9-verified)
  const char* Lb = (const char*)L;
  int colx = (lk*16) ^ (((lr>>1)&3)*16);
  int arow = lr*64 + colx;
  int brow = ((wn&1)*64 + lr)*64 + colx;

  // prologue: stage tiles 0,1,2 (12 loads), wait tile 0 landed
  STG_A(0); STG_B(0);
  STG_A(1); STG_B(1);
  STG_A(2); STG_B(2);
  asm volatile("s_waitcnt vmcnt(8)" ::: "memory");
  __builtin_amdgcn_sched_barrier(0);
  BAR();

  for (int t = 0; t < NT; ++t){
    int buf = t & 3;
    int Abase = (buf*4 + wm) << 13;
    int Bbase = (buf*4 + 2 + (wn>>1)) << 13;
    bool st = (t <= NT-4);
    if (st) { STG_A(t+3); STG_B(t+3); }

    bf16x8 a0,a1,a2,a3,a4,a5,a6,a7, b0,b1,b2,b3;
    a0 = *(const bf16x8*)(Lb + Abase + 0*1024 + arow);
    a1 = *(const bf16x8*)(Lb + Abase + 1*1024 + arow);
    a2 = *(const bf16x8*)(Lb + Abase + 2*1024 + arow);
    a3 = *(const bf16x8*)(Lb + Abase + 3*1024 + arow);
    a4 = *(const bf16x8*)(Lb + Abase + 4*1024 + arow);
    a5 = *(const bf16x8*)(Lb + Abase + 5*1024 + arow);
    a6 = *(const bf16x8*)(Lb + Abase + 6*1024 + arow);
    a7 = *(const bf16x8*)(Lb + Abase + 7*1024 + arow);
    b0 = *(const bf16x8*)(Lb + Bbase + 0*1024 + brow);
    b1 = *(const bf16x8*)(Lb + Bbase + 1*1024 + brow);
    b2 = *(const bf16x8*)(Lb + Bbase + 2*1024 + brow);
    b3 = *(const bf16x8*)(Lb + Bbase + 3*1024 + brow);

    __builtin_amdgcn_s_setprio(1);
    acc[0][0] = __builtin_amdgcn_mfma_f32_16x16x32_bf16(a0, b0, acc[0][0], 0,0,0);
    acc[0][1] = __builtin_amdgcn_mfma_f32_16x16x32_bf16(a0, b1, acc[0][1], 0,0,0);
    acc[0][2] = __builtin_amdgcn_mfma_f32_16x16x32_bf16(a0, b2, acc[0][2], 0,0,0);
    acc[0][3] = __builtin_amdgcn_mfma_f32_16x16x32_bf16(a0, b3, acc[0][3], 0,0,0);
    acc[1][0] = __builtin_amdgcn_mfma_f32_16x16x32_bf16(a1, b0, acc[1][0], 0,0,0);
    acc[1][1] = __builtin_amdgcn_mfma_f32_16x16x32_bf16(a1, b1, acc[1][1], 0,0,0);
    acc[1][2] = __builtin_amdgcn_mfma_f32_16x16x32_bf16(a1, b2, acc[1][2], 0,0,0);
    acc[1][3] = __builtin_amdgcn_mfma_f32_16x16x32_bf16(a1, b3, acc[1][3], 0,0,0);
    acc[2][0] = __builtin_amdgcn_mfma_f32_16x16x32_bf16(a2, b0, acc[2][0], 0,0,0);
    acc[2][1] = __builtin_amdgcn_mfma_f32_16x16x32_bf16(a2, b1, acc[2][1], 0,0,0);
    acc[2][2] = __builtin_amdgcn_mfma_f32_16x16x32_bf16(a2, b2, acc[2][2], 0,0,0);
    acc[2][3] = __builtin_amdgcn_mfma_f32_16x16x32_bf16(a2, b3, acc[2][3], 0,0,0);
    acc[3][0] = __builtin_amdgcn_mfma_f32_16x16x32_bf16(a3, b0, acc[3][0], 0,0,0);
    acc[3][1] = __builtin_amdgcn_mfma_f32_16x16x32_bf16(a3, b1, acc[3][1], 0,0,0);
    acc[3][2] = __builtin_amdgcn_mfma_f32_16x16x32_bf16(a3, b2, acc[3][2], 0,0,0);
    acc[3][3] = __builtin_amdgcn_mfma_f32_16x16x32_bf16(a3, b3, acc[3][3], 0,0,0);
    acc[4][0] = __builtin_amdgcn_mfma_f32_16x16x32_bf16(a4, b0, acc[4][0], 0,0,0);
    acc[4][1] = __builtin_amdgcn_mfma_f32_16x16x32_bf16(a4, b1, acc[4][1], 0,0,0);
    acc[4][2] = __builtin_amdgcn_mfma_f32_16x16x32_bf16(a4, b2, acc[4][2], 0,0,0);
    acc[4][3] = __builtin_amdgcn_mfma_f32_16x16x32_bf16(a4, b3, acc[4][3], 0,0,0);
    acc[5][0] = __builtin_amdgcn_mfma_f32_16x16x32_bf16(a5, b0, acc[5][0], 0,0,0);
    acc[5][1] = __builtin_amdgcn_mfma_f32_16x16x32_bf16(a5, b1, acc[5][1], 0,0,0);
    acc[5][2] = __builtin_amdgcn_mfma_f32_16x16x32_bf16(a5, b2, acc[5][2], 0,0,0);
    acc[5][3] = __builtin_amdgcn_mfma_f32_16x16x32_bf16(a5, b3, acc[5][3], 0,0,0);
    acc[6][0] = __builtin_amdgcn_mfma_f32_16x16x32_bf16(a6, b0, acc[6][0], 0,0,0);
    acc[6][1] = __builtin_amdgcn_mfma_f32_16x16x32_bf16(a6, b1, acc[6][1], 0,0,0);
    acc[6][2] = __builtin_amdgcn_mfma_f32_16x16x32_bf16(a6, b2, acc[6][2], 0,0,0);
    acc[6][3] = __builtin_amdgcn_mfma_f32_16x16x32_bf16(a6, b3, acc[6][3], 0,0,0);
    acc[7][0] = __builtin_amdgcn_mfma_f32_16x16x32_bf16(a7, b0, acc[7][0], 0,0,0);
    acc[7][1] = __builtin_amdgcn_mfma_f32_16x16x32_bf16(a7, b1, acc[7][1], 0,0,0);
    acc[7][2] = __builtin_amdgcn_mfma_f32_16x16x32_bf16(a7, b2, acc[7][2], 0,0,0);
    acc[7][3] = __builtin_amdgcn_mfma_f32_16x16x32_bf16(a7, b3, acc[7][3], 0,0,0);
    __builtin_amdgcn_s_setprio(0);

    // drain own LDS reads (cheap; they're consumed by now) — protects buf reuse across BAR
    asm volatile("s_waitcnt lgkmcnt(0)" ::: "memory");
    // counted vmcnt: ensure tile t+1 landed before next iteration reads it
    if (t <= NT-4)      { asm volatile("s_waitcnt vmcnt(8)" ::: "memory"); }
    else if (t == NT-3) { asm volatile("s_waitcnt vmcnt(4)" ::: "memory"); }
    else if (t == NT-2) { asm volatile("s_waitcnt vmcnt(0)" ::: "memory"); }
    __builtin_amdgcn_sched_barrier(0);
    BAR();
  }
#undef STG_A
#undef STG_B

  // ---- epilogue (r9-verified): LDS-staged coalesced C writes (512B row-runs)
  {
    u16* reg = &L[w*8192];
    #pragma unroll
    for (int nf=0; nf<4; ++nf){
      int col = nf*16 + lr;
      float bv = bias[n0 + wn*64 + col];
      #pragma unroll
      for (int mi=0; mi<8; ++mi){
        #pragma unroll
        for (int r=0;r<4;r++){
          int rr = mi*16 + lk*4 + r;
          reg[rr*64 + (col ^ ((rr&7)<<3))] = f2bu(acc[mi][nf][r] + bv);
        }
      }
    }
    asm volatile("s_waitcnt lgkmcnt(0)" ::: "memory");
    BAR();
    int co = (tid&31)*8;
    int rgn_c = co>>6;
    int c6 = co&63;
    #pragma unroll
    for (int p=0; p<16; ++p){
      int rI = p*16 + (tid>>5);
      int wreg = ((rI>>7)<<2) + rgn_c;
      int rr = rI & 127;
      const u16* src = &L[wreg*8192 + rr*64 + (c6 ^ ((rr&7)<<3))];
      uint4 v = *(const uint4*)src;
      *(uint4*)&Q[(size_t)(m0+rI)*N + n0 + co] = v;
    }
  }
}

// ---------------- per-token head-attention (bf16 qkv input; r4/r7/r9 verified) ----------------
__device__ inline void load16fb(const u16* p, float* f){
  uint4 a = ((const uint4*)p)[0], b4 = ((const uint4*)p)[1];
  f[0]=bl(a.x);  f[1]=bh(a.x);  f[2]=bl(a.y);  f[3]=bh(a.y);
  f[4]=bl(a.z);  f[5]=bh(a.z);  f[6]=bl(a.w);  f[7]=bh(a.w);
  f[8]=bl(b4.x); f[9]=bh(b4.x); f[10]=bl(b4.y);f[11]=bh(b4.y);
  f[12]=bl(b4.z);f[13]=bh(b4.z);f[14]=bl(b4.w);f[15]=bh(b4.w);
}

// 1 wave per token; lane = h*4 + dq; dq owns d in [dq*16, dq*16+16).
__global__ __launch_bounds__(256) void k_attn(const u16* __restrict__ Qkv,
                                              float* __restrict__ out){
  __shared__ __align__(16) u16 sm[4][3072];
  int w = threadIdx.x>>6, lane = threadIdx.x&63;
  int token = blockIdx.x*4 + w;
  const uint4* src = (const uint4*)(Qkv + (size_t)token*3072);
  uint4* dst = (uint4*)&sm[w][0];
  for (int i = lane; i < 384; i += 64) dst[i] = src[i];
  __syncthreads();

  int h = lane>>2, dq = lane&3;
  const u16* base = &sm[w][0];
  float qf[16];
  load16fb(base + h*192 + dq*16, qf);

  const float scale = 0.07216878364870323f;  // 1/sqrt(192)
  float s[16];
  #pragma unroll
  for (int g=0; g<16; ++g){
    float kf[16];
    load16fb(base + g*192 + 64 + dq*16, kf);
    float a = 0.f;
    #pragma unroll
    for (int j=0;j<16;j++) a += qf[j]*kf[j];
    a += __shfl_xor(a, 1);
    a += __shfl_xor(a, 2);
    s[g] = a * scale;
  }
  float mx = s[0];
  #pragma unroll
  for (int g=1; g<16; ++g) mx = fmaxf(mx, s[g]);
  float sum = 0.f;
  #pragma unroll
  for (int g=0; g<16; ++g){ s[g] = __expf(s[g]-mx); sum += s[g]; }
  float inv = 1.f/sum;

  float o[16];
  #pragma unroll
  for (int j=0;j<16;j++) o[j] = 0.f;
  #pragma unroll
  for (int g=0; g<16; ++g){
    float wg = s[g]*inv;
    float vf[16];
    load16fb(base + g*192 + 128 + dq*16, vf);
    #pragma unroll
    for (int j=0;j<16;j++) o[j] += wg*vf[j];
  }
  float* op = out + (size_t)token*1024 + h*64 + dq*16;
  #pragma unroll
  for (int i=0;i<4;i++)
    ((float4*)op)[i] = make_float4(o[i*4], o[i*4+1], o[i*4+2], o[i*4+3]);
}

// ---------------- fallback (ws too small): fully fused, f32 VALU, slow but correct ----------------
__global__ __launch_bounds__(256) void k_fallback(const float* __restrict__ X,
                                                  const float* __restrict__ W,
                                                  const float* __restrict__ bias,
                                                  float* __restrict__ out){
  int token = blockIdx.x;
  __shared__ float xs[1024];
  __shared__ float qkvs[3072];
  __shared__ float ss[16][16];
  __shared__ float ww[16][16];
  for (int i=threadIdx.x; i<1024; i+=256) xs[i] = X[(size_t)token*1024 + i];
  __syncthreads();
  for (int n=threadIdx.x; n<3072; n+=256){
    float acc = bias[n];
    for (int k=0;k<1024;k++) acc += xs[k]*W[(size_t)k*3072 + n];
    qkvs[n] = acc;
  }
  __syncthreads();
  {
    int t = threadIdx.x, h = t>>4, g = t&15;
    float a = 0.f;
    for (int d=0; d<64; d++) a += qkvs[h*192 + d]*qkvs[g*192 + 64 + d];
    ss[h][g] = a * 0.07216878364870323f;
  }
  __syncthreads();
  if (threadIdx.x < 16){
    int hh = threadIdx.x;
    float m = -1e30f;
    for (int g=0;g<16;g++) m = fmaxf(m, ss[hh][g]);
    float sum = 0.f;
    for (int g=0;g<16;g++){ float e = __expf(ss[hh][g]-m); ww[hh][g]=e; sum+=e; }
    float inv = 1.f/sum;
    for (int g=0;g<16;g++) ww[hh][g] *= inv;
  }
  __syncthreads();
  for (int i=threadIdx.x; i<1024; i+=256){
    int h = i>>6, d = i&63;
    float a = 0.f;
    for (int g=0;g<16;g++) a += ww[h][g]*qkvs[g*192 + 128 + d];
    out[(size_t)token*1024 + i] = a;
  }
}

extern "C" void kernel_launch(void* const* d_in, const int* in_sizes, int n_in,
                              void* d_out, int out_size, void* d_ws, size_t ws_size,
                              hipStream_t stream){
  const float* x    = (const float*)d_in[0];   // [4,4096,1024] f32
  const float* wk   = (const float*)d_in[1];   // [1024,16,192] f32
  const float* bias = (const float*)d_in[2];   // [16,192] f32
  float* out = (float*)d_out;                  // [4,4096,16,64] f32

  const size_t offW = 33554432;                       // Xb: 16M bf16
  const size_t offQ = offW + 6291456;                 // Wt: 3M bf16
  const size_t need = offQ + (size_t)16384*3072*2;    // Q bf16

  if (ws_size >= need){
    u16* Xb = (u16*)d_ws;
    u16* Wt = (u16*)((char*)d_ws + offW);
    u16* Q  = (u16*)((char*)d_ws + offQ);
    k_conv  <<<5120, 256, 0, stream>>>(x, Xb, wk, Wt);
    k_gemm2 <<<768, 512, 0, stream>>>(Xb, Wt, bias, Q);
    k_attn  <<<4096, 256, 0, stream>>>(Q, out);
  } else {
    k_fallback<<<16384, 256, 0, stream>>>(x, wk, bias, out);
  }
}

// Round 11
// 190.877 us; speedup vs baseline: 1.4437x; 1.0054x over previous
//
#include <hip/hip_runtime.h>
#include <cstdint>
#include <cstddef>

typedef unsigned short u16;
typedef __attribute__((ext_vector_type(8))) short bf16x8;
typedef __attribute__((ext_vector_type(4))) float f32x4;

__device__ inline float bl(uint32_t u){ union{float f;uint32_t i;}c; c.i = u<<16; return c.f; }
__device__ inline float bh(uint32_t u){ union{float f;uint32_t i;}c; c.i = u & 0xFFFF0000u; return c.f; }
__device__ inline u16 f2bu(float f){
  union{float f;uint32_t u;} c; c.f=f;
  uint32_t u=c.u;
  return (u16)((u + 0x7FFFu + ((u>>16)&1u))>>16);  // RNE
}

#define GLOAD_LDS16(g, l) __builtin_amdgcn_global_load_lds( \
    (__attribute__((address_space(1))) void*)(g), \
    (__attribute__((address_space(3))) void*)(l), 16, 0, 0)
#define BAR() do{ asm volatile("" ::: "memory"); __builtin_amdgcn_s_barrier(); asm volatile("" ::: "memory"); }while(0)

// ---------------- fused convert: X f32->bf16 (blocks 0..2047) + W transpose (blocks 2048..5119) --
__global__ __launch_bounds__(256) void k_conv(const float* __restrict__ X,
                                              u16* __restrict__ Xb,
                                              const float* __restrict__ W,
                                              u16* __restrict__ Wt){
  __shared__ float t[32][33];
  int b = blockIdx.x;
  if (b < 2048){
    int i = b*256 + threadIdx.x;
    for (; i < 4194304; i += 2048*256){
      float4 v = ((const float4*)X)[i];
      ushort4 o;
      o.x=f2bu(v.x); o.y=f2bu(v.y); o.z=f2bu(v.z); o.w=f2bu(v.w);
      ((ushort4*)Xb)[i] = o;
    }
  } else {
    int bb = b - 2048;                 // 0..3071
    int n0 = (bb % 96)*32, k0 = (bb / 96)*32;
    int tx = threadIdx.x & 31, ty = threadIdx.x >> 5;
    #pragma unroll
    for (int i=0;i<32;i+=8)
      t[ty+i][tx] = W[(size_t)(k0+ty+i)*3072 + n0+tx];
    __syncthreads();
    #pragma unroll
    for (int i=0;i<32;i+=8)
      Wt[(size_t)(n0+ty+i)*1024 + k0+tx] = f2bu(t[tx][ty+i]);
  }
}

// ---------------- GEMM: Qkv[16384][3072] = Xb[M][K]*Wt[N][K]^T + bias, bf16 out ----------------
// r10 verified loop (115us, Mfma 38.5%) upgraded: 5 LDS buffers (160KB = full pool), ONE barrier
// per 2 K-tiles (2-tile wave-drift window). Hazard-safe: drift<=2 tiles, STG(t+3/t+4) in window
// {t,t+1} overwrite tiles t-2/t-1 whose readers finished before window entry. vmcnt(4) at window
// end leaves only STG(t+4) in flight -> tiles t+2,t+3 guaranteed at next window entry.
__global__ __launch_bounds__(512, 1) void k_gemm2(const u16* __restrict__ Xb,
                                                  const u16* __restrict__ Wt,
                                                  const float* __restrict__ bias,
                                                  u16* __restrict__ Q){
  __shared__ __align__(16) u16 L[81920];   // 5 bufs x [A0,A1,B0,B1][4096 u16] = 160 KiB
  const int K = 1024, N = 3072, NT = 32;
  int b = blockIdx.x;
  // XCD swizzle: nwg=768, 768%8==0 -> bijective
  int swz = (b & 7)*96 + (b >> 3);
  int bm = swz / 12, bn = swz % 12;
  int m0 = bm*256, n0 = bn*256;
  int tid = threadIdx.x, w = tid>>6, lane = tid&63, lr = lane&15, lk = lane>>4;
  int wm = w>>2, wn = w&3;

  f32x4 acc[8][4];
  #pragma unroll
  for (int i=0;i<8;i++)
    #pragma unroll
    for (int j=0;j<4;j++)
      acc[i][j] = (f32x4){0.f,0.f,0.f,0.f};

  // ---- staging source (inverse-swizzled, r8-r10 verified)
  int grow = tid>>2;
  int gcol = ((((tid&3)*16) ^ (((tid>>3)&1)<<4) ^ (((tid>>4)&1)<<5)) >> 1);
  const u16* gA0 = Xb + (size_t)(m0 + grow)*K + gcol;
  const u16* gA1 = Xb + (size_t)(m0 + 128 + grow)*K + gcol;
  const u16* gB0 = Wt + (size_t)(n0 + grow)*K + gcol;
  const u16* gB1 = Wt + (size_t)(n0 + 128 + grow)*K + gcol;

#define STG(j) do{ int bf=(j)%5, kof=(j)*32; \
    GLOAD_LDS16(gA0+kof, &L[((bf*4+0)<<12) + tid*8]); \
    GLOAD_LDS16(gA1+kof, &L[((bf*4+1)<<12) + tid*8]); \
    GLOAD_LDS16(gB0+kof, &L[((bf*4+2)<<12) + tid*8]); \
    GLOAD_LDS16(gB1+kof, &L[((bf*4+3)<<12) + tid*8]); }while(0)

  // ---- read-side swizzled addressing (r8-r10 verified)
  const char* Lb = (const char*)L;
  int colx = (lk*16) ^ (((lr>>1)&3)*16);
  int arow = lr*64 + colx;
  int brow = ((wn&1)*64 + lr)*64 + colx;

#define TILE_BODY(bufidx) do{ \
    int Abase = ((bufidx)*4 + wm) << 13; \
    int Bbase = ((bufidx)*4 + 2 + (wn>>1)) << 13; \
    bf16x8 a0,a1,a2,a3,a4,a5,a6,a7, b0,b1,b2,b3; \
    a0 = *(const bf16x8*)(Lb + Abase + 0*1024 + arow); \
    a1 = *(const bf16x8*)(Lb + Abase + 1*1024 + arow); \
    a2 = *(const bf16x8*)(Lb + Abase + 2*1024 + arow); \
    a3 = *(const bf16x8*)(Lb + Abase + 3*1024 + arow); \
    a4 = *(const bf16x8*)(Lb + Abase + 4*1024 + arow); \
    a5 = *(const bf16x8*)(Lb + Abase + 5*1024 + arow); \
    a6 = *(const bf16x8*)(Lb + Abase + 6*1024 + arow); \
    a7 = *(const bf16x8*)(Lb + Abase + 7*1024 + arow); \
    b0 = *(const bf16x8*)(Lb + Bbase + 0*1024 + brow); \
    b1 = *(const bf16x8*)(Lb + Bbase + 1*1024 + brow); \
    b2 = *(const bf16x8*)(Lb + Bbase + 2*1024 + brow); \
    b3 = *(const bf16x8*)(Lb + Bbase + 3*1024 + brow); \
    __builtin_amdgcn_s_setprio(1); \
    acc[0][0] = __builtin_amdgcn_mfma_f32_16x16x32_bf16(a0, b0, acc[0][0], 0,0,0); \
    acc[0][1] = __builtin_amdgcn_mfma_f32_16x16x32_bf16(a0, b1, acc[0][1], 0,0,0); \
    acc[0][2] = __builtin_amdgcn_mfma_f32_16x16x32_bf16(a0, b2, acc[0][2], 0,0,0); \
    acc[0][3] = __builtin_amdgcn_mfma_f32_16x16x32_bf16(a0, b3, acc[0][3], 0,0,0); \
    acc[1][0] = __builtin_amdgcn_mfma_f32_16x16x32_bf16(a1, b0, acc[1][0], 0,0,0); \
    acc[1][1] = __builtin_amdgcn_mfma_f32_16x16x32_bf16(a1, b1, acc[1][1], 0,0,0); \
    acc[1][2] = __builtin_amdgcn_mfma_f32_16x16x32_bf16(a1, b2, acc[1][2], 0,0,0); \
    acc[1][3] = __builtin_amdgcn_mfma_f32_16x16x32_bf16(a1, b3, acc[1][3], 0,0,0); \
    acc[2][0] = __builtin_amdgcn_mfma_f32_16x16x32_bf16(a2, b0, acc[2][0], 0,0,0); \
    acc[2][1] = __builtin_amdgcn_mfma_f32_16x16x32_bf16(a2, b1, acc[2][1], 0,0,0); \
    acc[2][2] = __builtin_amdgcn_mfma_f32_16x16x32_bf16(a2, b2, acc[2][2], 0,0,0); \
    acc[2][3] = __builtin_amdgcn_mfma_f32_16x16x32_bf16(a2, b3, acc[2][3], 0,0,0); \
    acc[3][0] = __builtin_amdgcn_mfma_f32_16x16x32_bf16(a3, b0, acc[3][0], 0,0,0); \
    acc[3][1] = __builtin_amdgcn_mfma_f32_16x16x32_bf16(a3, b1, acc[3][1], 0,0,0); \
    acc[3][2] = __builtin_amdgcn_mfma_f32_16x16x32_bf16(a3, b2, acc[3][2], 0,0,0); \
    acc[3][3] = __builtin_amdgcn_mfma_f32_16x16x32_bf16(a3, b3, acc[3][3], 0,0,0); \
    acc[4][0] = __builtin_amdgcn_mfma_f32_16x16x32_bf16(a4, b0, acc[4][0], 0,0,0); \
    acc[4][1] = __builtin_amdgcn_mfma_f32_16x16x32_bf16(a4, b1, acc[4][1], 0,0,0); \
    acc[4][2] = __builtin_amdgcn_mfma_f32_16x16x32_bf16(a4, b2, acc[4][2], 0,0,0); \
    acc[4][3] = __builtin_amdgcn_mfma_f32_16x16x32_bf16(a4, b3, acc[4][3], 0,0,0); \
    acc[5][0] = __builtin_amdgcn_mfma_f32_16x16x32_bf16(a5, b0, acc[5][0], 0,0,0); \
    acc[5][1] = __builtin_amdgcn_mfma_f32_16x16x32_bf16(a5, b1, acc[5][1], 0,0,0); \
    acc[5][2] = __builtin_amdgcn_mfma_f32_16x16x32_bf16(a5, b2, acc[5][2], 0,0,0); \
    acc[5][3] = __builtin_amdgcn_mfma_f32_16x16x32_bf16(a5, b3, acc[5][3], 0,0,0); \
    acc[6][0] = __builtin_amdgcn_mfma_f32_16x16x32_bf16(a6, b0, acc[6][0], 0,0,0); \
    acc[6][1] = __builtin_amdgcn_mfma_f32_16x16x32_bf16(a6, b1, acc[6][1], 0,0,0); \
    acc[6][2] = __builtin_amdgcn_mfma_f32_16x16x32_bf16(a6, b2, acc[6][2], 0,0,0); \
    acc[6][3] = __builtin_amdgcn_mfma_f32_16x16x32_bf16(a6, b3, acc[6][3], 0,0,0); \
    acc[7][0] = __builtin_amdgcn_mfma_f32_16x16x32_bf16(a7, b0, acc[7][0], 0,0,0); \
    acc[7][1] = __builtin_amdgcn_mfma_f32_16x16x32_bf16(a7, b1, acc[7][1], 0,0,0); \
    acc[7][2] = __builtin_amdgcn_mfma_f32_16x16x32_bf16(a7, b2, acc[7][2], 0,0,0); \
    acc[7][3] = __builtin_amdgcn_mfma_f32_16x16x32_bf16(a7, b3, acc[7][3], 0,0,0); \
    __builtin_amdgcn_s_setprio(0); }while(0)

  // prologue: stage tiles 0,1,2 (12 loads); vmcnt(4) -> tiles 0,1 landed (STG(2) in flight)
  STG(0); STG(1); STG(2);
  asm volatile("s_waitcnt vmcnt(4)" ::: "memory");
  __builtin_amdgcn_sched_barrier(0);
  BAR();

  for (int t = 0; t < NT; t += 2){
    if (t+3 < NT) STG(t+3);
    TILE_BODY(t%5);
    if (t+4 < NT) STG(t+4);
    TILE_BODY((t+1)%5);
    asm volatile("s_waitcnt lgkmcnt(0)" ::: "memory");
    if      (t+4 < NT) { asm volatile("s_waitcnt vmcnt(4)" ::: "memory"); }
    else if (t+2 < NT) { asm volatile("s_waitcnt vmcnt(0)" ::: "memory"); }
    __builtin_amdgcn_sched_barrier(0);
    BAR();
  }
#undef STG
#undef TILE_BODY

  // ---- epilogue (r9/r10-verified): LDS-staged coalesced C writes (512B row-runs)
  {
    u16* reg = &L[w*8192];
    #pragma unroll
    for (int nf=0; nf<4; ++nf){
      int col = nf*16 + lr;
      float bv = bias[n0 + wn*64 + col];
      #pragma unroll
      for (int mi=0; mi<8; ++mi){
        #pragma unroll
        for (int r=0;r<4;r++){
          int rr = mi*16 + lk*4 + r;
          reg[rr*64 + (col ^ ((rr&7)<<3))] = f2bu(acc[mi][nf][r] + bv);
        }
      }
    }
    asm volatile("s_waitcnt lgkmcnt(0)" ::: "memory");
    BAR();
    int co = (tid&31)*8;
    int rgn_c = co>>6;
    int c6 = co&63;
    #pragma unroll
    for (int p=0; p<16; ++p){
      int rI = p*16 + (tid>>5);
      int wreg = ((rI>>7)<<2) + rgn_c;
      int rr = rI & 127;
      const u16* src = &L[wreg*8192 + rr*64 + (c6 ^ ((rr&7)<<3))];
      uint4 v = *(const uint4*)src;
      *(uint4*)&Q[(size_t)(m0+rI)*N + n0 + co] = v;
    }
  }
}

// ---------------- per-token head-attention (bf16 qkv input; r4/r7/r9 verified) ----------------
__device__ inline void load16fb(const u16* p, float* f){
  uint4 a = ((const uint4*)p)[0], b4 = ((const uint4*)p)[1];
  f[0]=bl(a.x);  f[1]=bh(a.x);  f[2]=bl(a.y);  f[3]=bh(a.y);
  f[4]=bl(a.z);  f[5]=bh(a.z);  f[6]=bl(a.w);  f[7]=bh(a.w);
  f[8]=bl(b4.x); f[9]=bh(b4.x); f[10]=bl(b4.y);f[11]=bh(b4.y);
  f[12]=bl(b4.z);f[13]=bh(b4.z);f[14]=bl(b4.w);f[15]=bh(b4.w);
}

// 1 wave per token; lane = h*4 + dq; dq owns d in [dq*16, dq*16+16).
__global__ __launch_bounds__(256) void k_attn(const u16* __restrict__ Qkv,
                                              float* __restrict__ out){
  __shared__ __align__(16) u16 sm[4][3072];
  int w = threadIdx.x>>6, lane = threadIdx.x&63;
  int token = blockIdx.x*4 + w;
  const uint4* src = (const uint4*)(Qkv + (size_t)token*3072);
  uint4* dst = (uint4*)&sm[w][0];
  for (int i = lane; i < 384; i += 64) dst[i] = src[i];
  __syncthreads();

  int h = lane>>2, dq = lane&3;
  const u16* base = &sm[w][0];
  float qf[16];
  load16fb(base + h*192 + dq*16, qf);

  const float scale = 0.07216878364870323f;  // 1/sqrt(192)
  float s[16];
  #pragma unroll
  for (int g=0; g<16; ++g){
    float kf[16];
    load16fb(base + g*192 + 64 + dq*16, kf);
    float a = 0.f;
    #pragma unroll
    for (int j=0;j<16;j++) a += qf[j]*kf[j];
    a += __shfl_xor(a, 1);
    a += __shfl_xor(a, 2);
    s[g] = a * scale;
  }
  float mx = s[0];
  #pragma unroll
  for (int g=1; g<16; ++g) mx = fmaxf(mx, s[g]);
  float sum = 0.f;
  #pragma unroll
  for (int g=0; g<16; ++g){ s[g] = __expf(s[g]-mx); sum += s[g]; }
  float inv = 1.f/sum;

  float o[16];
  #pragma unroll
  for (int j=0;j<16;j++) o[j] = 0.f;
  #pragma unroll
  for (int g=0; g<16; ++g){
    float wg = s[g]*inv;
    float vf[16];
    load16fb(base + g*192 + 128 + dq*16, vf);
    #pragma unroll
    for (int j=0;j<16;j++) o[j] += wg*vf[j];
  }
  float* op = out + (size_t)token*1024 + h*64 + dq*16;
  #pragma unroll
  for (int i=0;i<4;i++)
    ((float4*)op)[i] = make_float4(o[i*4], o[i*4+1], o[i*4+2], o[i*4+3]);
}

// ---------------- fallback (ws too small): fully fused, f32 VALU, slow but correct ----------------
__global__ __launch_bounds__(256) void k_fallback(const float* __restrict__ X,
                                                  const float* __restrict__ W,
                                                  const float* __restrict__ bias,
                                                  float* __restrict__ out){
  int token = blockIdx.x;
  __shared__ float xs[1024];
  __shared__ float qkvs[3072];
  __shared__ float ss[16][16];
  __shared__ float ww[16][16];
  for (int i=threadIdx.x; i<1024; i+=256) xs[i] = X[(size_t)token*1024 + i];
  __syncthreads();
  for (int n=threadIdx.x; n<3072; n+=256){
    float acc = bias[n];
    for (int k=0;k<1024;k++) acc += xs[k]*W[(size_t)k*3072 + n];
    qkvs[n] = acc;
  }
  __syncthreads();
  {
    int t = threadIdx.x, h = t>>4, g = t&15;
    float a = 0.f;
    for (int d=0; d<64; d++) a += qkvs[h*192 + d]*qkvs[g*192 + 64 + d];
    ss[h][g] = a * 0.07216878364870323f;
  }
  __syncthreads();
  if (threadIdx.x < 16){
    int hh = threadIdx.x;
    float m = -1e30f;
    for (int g=0;g<16;g++) m = fmaxf(m, ss[hh][g]);
    float sum = 0.f;
    for (int g=0;g<16;g++){ float e = __expf(ss[hh][g]-m); ww[hh][g]=e; sum+=e; }
    float inv = 1.f/sum;
    for (int g=0;g<16;g++) ww[hh][g] *= inv;
  }
  __syncthreads();
  for (int i=threadIdx.x; i<1024; i+=256){
    int h = i>>6, d = i&63;
    float a = 0.f;
    for (int g=0;g<16;g++) a += ww[h][g]*qkvs[g*192 + 128 + d];
    out[(size_t)token*1024 + i] = a;
  }
}

extern "C" void kernel_launch(void* const* d_in, const int* in_sizes, int n_in,
                              void* d_out, int out_size, void* d_ws, size_t ws_size,
                              hipStream_t stream){
  const float* x    = (const float*)d_in[0];   // [4,4096,1024] f32
  const float* wk   = (const float*)d_in[1];   // [1024,16,192] f32
  const float* bias = (const float*)d_in[2];   // [16,192] f32
  float* out = (float*)d_out;                  // [4,4096,16,64] f32

  const size_t offW = 33554432;                       // Xb: 16M bf16
  const size_t offQ = offW + 6291456;                 // Wt: 3M bf16
  const size_t need = offQ + (size_t)16384*3072*2;    // Q bf16

  if (ws_size >= need){
    u16* Xb = (u16*)d_ws;
    u16* Wt = (u16*)((char*)d_ws + offW);
    u16* Q  = (u16*)((char*)d_ws + offQ);
    k_conv  <<<5120, 256, 0, stream>>>(x, Xb, wk, Wt);
    k_gemm2 <<<768, 512, 0, stream>>>(Xb, Wt, bias, Q);
    k_attn  <<<4096, 256, 0, stream>>>(Q, out);
  } else {
    k_fallback<<<16384, 256, 0, stream>>>(x, wk, bias, out);
  }
}